// Round 4
// baseline (369.689 us; speedup 1.0000x reference)
//
#include <hip/hip_runtime.h>

// ---------- fp32 <-> bf16 helpers ----------
__device__ __forceinline__ float bf2f(unsigned short u) {
    union { unsigned int i; float f; } v;
    v.i = ((unsigned int)u) << 16;
    return v.f;
}
__device__ __forceinline__ unsigned short f2bf(float f) {
    union { float f; unsigned int i; } v;
    v.f = f;
    unsigned int x = v.i;
    return (unsigned short)((x + 0x7fffu + ((x >> 16) & 1u)) >> 16);
}

typedef short bf16x8 __attribute__((ext_vector_type(8)));
typedef float f32x4 __attribute__((ext_vector_type(4)));

// bucket geometry: 512 nodes per bucket (shift 9); NB = ceil(M/512) <= 256
#define BSHIFT 9
#define BRANGE 512

// ---------- prep: zero deg+bcnt, x fp32->bf16, W panels -> bf16 ----------
__global__ void prep_kernel(const float* __restrict__ x,
                            const float* __restrict__ W1, const float* __restrict__ W2,
                            const float* __restrict__ W3, const float* __restrict__ W4,
                            unsigned short* __restrict__ xb, unsigned short* __restrict__ Wb,
                            int* __restrict__ deg, int* __restrict__ bcnt, int M, int nx4)
{
    int i = blockIdx.x * 256 + threadIdx.x;
    if (i < nx4) {
        float4 v = ((const float4*)x)[i];
        unsigned lo = (unsigned)f2bf(v.x) | ((unsigned)f2bf(v.y) << 16);
        unsigned hi = (unsigned)f2bf(v.z) | ((unsigned)f2bf(v.w) << 16);
        uint2 p; p.x = lo; p.y = hi;
        *(uint2*)(xb + (size_t)i * 4) = p;
    }
    if (i < M) deg[i] = 0;
    if (bcnt && i < 256) bcnt[i] = 0;
    if (i < 16384) {
        Wb[i]         = f2bf(W1[i]);
        Wb[16384 + i] = f2bf(W2[i]);
        Wb[32768 + i] = f2bf(W3[i] + W4[i]);
    }
}

// ---------- bucketed CSR build (atomic-poor) ----------
__global__ __launch_bounds__(512) void bucket_hist_kernel(
    const int* __restrict__ dst, int* __restrict__ bcnt, int ne, int nb)
{
    __shared__ int h[256];
    int t = threadIdx.x;
    if (t < 256) h[t] = 0;
    __syncthreads();
    for (int i = blockIdx.x * 512 + t; i < ne; i += gridDim.x * 512)
        atomicAdd(&h[dst[i] >> BSHIFT], 1);
    __syncthreads();
    if (t < nb) {
        int c = h[t];
        if (c) atomicAdd(&bcnt[t], c);
    }
}

__global__ __launch_bounds__(256) void bucket_scan_kernel(
    const int* __restrict__ bcnt, int* __restrict__ boff, int* __restrict__ gcur, int nb)
{
    __shared__ int sh[256];
    int t = threadIdx.x;
    int v = (t < nb) ? bcnt[t] : 0;
    sh[t] = v;
    __syncthreads();
    int acc = v;
    for (int off = 1; off < 256; off <<= 1) {
        int y = (t >= off) ? sh[t - off] : 0;
        __syncthreads();
        acc += y;
        sh[t] = acc;
        __syncthreads();
    }
    if (t < nb) {
        boff[t + 1] = acc;        // inclusive
        gcur[t] = acc - v;        // exclusive: region cursor
    }
    if (t == 0) boff[0] = 0;
}

// Partition edges into dst-range buckets. Per block: LDS count pass, ONE global
// atomic per touched bucket to claim a contiguous run, then LDS-cursor scatter.
__global__ __launch_bounds__(512) void bucketize_kernel(
    const int* __restrict__ src, const int* __restrict__ dst,
    int* __restrict__ gcur, int2* __restrict__ bucketed, int ne, int chunk)
{
    __shared__ int cnt[256];
    __shared__ int sbase[256];
    const int t = threadIdx.x;
    const int e0 = blockIdx.x * chunk;
    const int e1 = (e0 + chunk < ne) ? e0 + chunk : ne;

    if (t < 256) cnt[t] = 0;
    __syncthreads();
    for (int e = e0 + t; e < e1; e += 512)
        atomicAdd(&cnt[dst[e] >> BSHIFT], 1);
    __syncthreads();
    if (t < 256) {
        int c = cnt[t];
        sbase[t] = c ? atomicAdd(&gcur[t], c) : 0;
        cnt[t] = 0;
    }
    __syncthreads();
    for (int e = e0 + t; e < e1; e += 512) {
        int d = dst[e];
        int b = d >> BSHIFT;
        int loc = atomicAdd(&cnt[b], 1);
        int2 v; v.x = src[e]; v.y = d;
        bucketed[sbase[b] + loc] = v;
    }
}

// one block per bucket: LDS histogram over the bucket's 512-node range -> deg
__global__ __launch_bounds__(512) void bucket_count_kernel(
    const int2* __restrict__ bucketed, const int* __restrict__ boff,
    int* __restrict__ deg, int M)
{
    __shared__ int cnt[BRANGE];
    const int t = threadIdx.x;
    const int b = blockIdx.x;
    cnt[t] = 0;
    __syncthreads();
    const int lo = boff[b], hi = boff[b + 1];
    for (int i = lo + t; i < hi; i += 512)
        atomicAdd(&cnt[bucketed[i].y & (BRANGE - 1)], 1);
    __syncthreads();
    int node = (b << BSHIFT) + t;
    if (node < M) deg[node] = cnt[t];
}

// one block per bucket: LDS cursors seeded from offs, plain csr stores.
__global__ __launch_bounds__(512) void bucket_fill_kernel(
    const int2* __restrict__ bucketed, const int* __restrict__ boff,
    const int* __restrict__ offs, int* __restrict__ csr, int M)
{
    __shared__ int cur[BRANGE];
    const int t = threadIdx.x;
    const int b = blockIdx.x;
    int node = (b << BSHIFT) + t;
    cur[t] = (node < M) ? offs[node] : 0;
    __syncthreads();
    const int lo = boff[b], hi = boff[b + 1];
    for (int i = lo + t; i < hi; i += 512) {
        int2 e = bucketed[i];
        int p = atomicAdd(&cur[e.y & (BRANGE - 1)], 1);
        csr[p] = e.x;
    }
}

// ---------- fallback-path CSR build (atomic histogram + ranged fill) ----------
__global__ void hist_kernel(const int* __restrict__ dst, int* __restrict__ deg, int ne) {
    int e = blockIdx.x * blockDim.x + threadIdx.x;
    if (e < ne) atomicAdd(&deg[dst[e]], 1);
}

// coalesced 3-stage scan (98 blocks x 1024)
__global__ __launch_bounds__(1024) void scan_local_kernel(
    const int* __restrict__ deg, int* __restrict__ offs, int* __restrict__ bsum, int n)
{
    __shared__ int sh[1024];
    int t = threadIdx.x;
    int i = blockIdx.x * 1024 + t;
    int v = (i < n) ? deg[i] : 0;
    sh[t] = v;
    __syncthreads();
    int acc = v;
    for (int off = 1; off < 1024; off <<= 1) {
        int y = (t >= off) ? sh[t - off] : 0;
        __syncthreads();
        acc += y;
        sh[t] = acc;
        __syncthreads();
    }
    if (i < n) offs[i] = acc - v;  // exclusive within block
    if (t == 1023) bsum[blockIdx.x] = acc;
}

__global__ __launch_bounds__(128) void scan_totals_kernel(
    int* __restrict__ bsum, int* __restrict__ offs, int nb, int n)
{
    __shared__ int sh[128];
    int t = threadIdx.x;
    int v = (t < nb) ? bsum[t] : 0;
    sh[t] = v;
    __syncthreads();
    int acc = v;
    for (int off = 1; off < 128; off <<= 1) {
        int y = (t >= off) ? sh[t - off] : 0;
        __syncthreads();
        acc += y;
        sh[t] = acc;
        __syncthreads();
    }
    if (t < nb) bsum[t] = acc - v;   // exclusive block offsets, in place
    if (t == 127) offs[n] = acc;     // grand total == NE
}

// cursor may be null (bucketed fill path does not need it)
__global__ __launch_bounds__(1024) void scan_finalize_kernel(
    int* __restrict__ offs, const int* __restrict__ bsum, int* __restrict__ cursor, int n)
{
    int i = blockIdx.x * 1024 + threadIdx.x;
    if (i < n) {
        int o = offs[i] + bsum[i >> 10];
        offs[i] = o;
        if (cursor) cursor[i] = o;
    }
}

// fallback (low workspace): atomic-cursor ranged fill
__global__ __launch_bounds__(256) void fill_csr_ranged_kernel(
    const int* __restrict__ src, const int* __restrict__ dst,
    int* __restrict__ cursor, int* __restrict__ csr, int ne, int rangeSize)
{
    const int r = blockIdx.x & 7;
    const int cb = blockIdx.x >> 3;
    const int nchunk = gridDim.x >> 3;
    const unsigned lo = (unsigned)(r * rangeSize);
    for (int e = cb * 256 + threadIdx.x; e < ne; e += nchunk * 256) {
        int d = dst[e];
        int s = src[e];
        if ((unsigned)(d - lo) < (unsigned)rangeSize) {
            int pos = atomicAdd(&cursor[d], 1);
            csr[pos] = s;
        }
    }
}

// ---------- FUSED gather + 3-panel bf16 MFMA GEMM + fp32 epilogue ----------
// Per 64-row block: stage x tile -> LDS; each of 4 waves gathers 16 rows'
// neighbor sums (random 256B row reads, fp32 accum) straight into g_lds as
// bf16; in-degree (e1-e0) stashed in LDS (no deg[] reads, no gb round-trip).
// Then one barrier, 96 MFMAs/wave, fused epilogue:
// out = sigmoid(2*(P34 + d*(b3+b4))) * (2*(P2 + d*b2)) + P1 + b1
template<bool XBF16>
__global__ __launch_bounds__(256) void fused_gather_gemm_kernel(
    const void* __restrict__ xsrc, const int* __restrict__ offs,
    const int* __restrict__ csr, const unsigned short* __restrict__ Wb,
    const float* __restrict__ B1, const float* __restrict__ B2,
    const float* __restrict__ B3, const float* __restrict__ B4,
    float* __restrict__ out, int M)
{
    __shared__ unsigned short x_lds[64 * 136];
    __shared__ unsigned short g_lds[64 * 136];
    __shared__ float sdeg[64];

    const int t = threadIdx.x;
    const int wave = t >> 6;
    const int lane = t & 63;
    const int ln = lane & 15;
    const int quad = lane >> 4;
    const int row0 = blockIdx.x * 64;

    // ---- stage x tile ----
    if (XBF16) {
        const unsigned short* xb = (const unsigned short*)xsrc;
#pragma unroll
        for (int i = 0; i < 4; ++i) {
            int c = i * 256 + t;          // 1024 chunks of 16B
            int row = c >> 4;
            int koff = (c & 15) * 8;
            int grow = row0 + row;
            if (grow > M - 1) grow = M - 1;
            *(uint4*)&x_lds[row * 136 + koff] =
                *(const uint4*)(xb + (size_t)grow * 128 + koff);
        }
    } else {
        const float* xf = (const float*)xsrc;
#pragma unroll
        for (int i = 0; i < 8; ++i) {
            int c = i * 256 + t;          // 2048 chunks of float4
            int row = c >> 5;
            int koff = (c & 31) * 4;
            int grow = row0 + row;
            if (grow > M - 1) grow = M - 1;
            float4 v = *(const float4*)(xf + (size_t)grow * 128 + koff);
            unsigned p0 = (unsigned)f2bf(v.x) | ((unsigned)f2bf(v.y) << 16);
            unsigned p1 = (unsigned)f2bf(v.z) | ((unsigned)f2bf(v.w) << 16);
            *(unsigned*)&x_lds[row * 136 + koff]     = p0;
            *(unsigned*)&x_lds[row * 136 + koff + 2] = p1;
        }
    }

    // ---- gather phase: wave handles rows [wave*16, wave*16+16) ----
    for (int r = 0; r < 16; ++r) {
        const int row = wave * 16 + r;
        int node = row0 + row;
        if (node > M - 1) node = M - 1;
        const int e0 = offs[node];
        const int e1 = offs[node + 1];

        float s0 = 0.f, s1 = 0.f, t0 = 0.f, t1 = 0.f;
        for (int e = e0; e < e1; e += 8) {
            int id[8];
            float m[8];
#pragma unroll
            for (int j = 0; j < 8; ++j) {
                int ee = e + j;
                bool ok = ee < e1;
                id[j] = csr[ok ? ee : e1 - 1];
                m[j] = ok ? 1.f : 0.f;
            }
#pragma unroll
            for (int j = 0; j < 8; ++j) {
                float lo, hi;
                if (XBF16) {
                    unsigned v = *(const unsigned*)((const unsigned short*)xsrc +
                                                    (size_t)id[j] * 128 + lane * 2);
                    lo = bf2f((unsigned short)(v & 0xffffu));
                    hi = bf2f((unsigned short)(v >> 16));
                } else {
                    float2 v = *(const float2*)((const float*)xsrc +
                                                (size_t)id[j] * 128 + lane * 2);
                    lo = v.x;
                    hi = v.y;
                }
                if (j & 1) { t0 += m[j] * lo; t1 += m[j] * hi; }
                else       { s0 += m[j] * lo; s1 += m[j] * hi; }
            }
        }
        unsigned pk = (unsigned)f2bf(s0 + t0) | ((unsigned)f2bf(s1 + t1) << 16);
        *(unsigned*)&g_lds[row * 136 + lane * 2] = pk;
        if (lane == 0) sdeg[row] = (float)(e1 - e0);
    }
    __syncthreads();

    // ---- 3-panel GEMM: wave owns cols [wave*32, wave*32+32) ----
    f32x4 acc[3][4][2];
#pragma unroll
    for (int p = 0; p < 3; ++p)
#pragma unroll
        for (int rt = 0; rt < 4; ++rt)
#pragma unroll
            for (int c = 0; c < 2; ++c) {
                acc[p][rt][c][0] = 0.f; acc[p][rt][c][1] = 0.f;
                acc[p][rt][c][2] = 0.f; acc[p][rt][c][3] = 0.f;
            }

#pragma unroll
    for (int kk = 0; kk < 4; ++kk) {
        bf16x8 ax[4], ag[4];
#pragma unroll
        for (int rt = 0; rt < 4; ++rt) {
            ax[rt] = *(const bf16x8*)&x_lds[(rt * 16 + ln) * 136 + kk * 32 + quad * 8];
            ag[rt] = *(const bf16x8*)&g_lds[(rt * 16 + ln) * 136 + kk * 32 + quad * 8];
        }
#pragma unroll
        for (int p = 0; p < 3; ++p) {
#pragma unroll
            for (int c = 0; c < 2; ++c) {
                int col = wave * 32 + c * 16 + ln;
                bf16x8 bw = *(const bf16x8*)(Wb + (size_t)p * 16384 +
                                             (size_t)col * 128 + kk * 32 + quad * 8);
#pragma unroll
                for (int rt = 0; rt < 4; ++rt) {
                    acc[p][rt][c] = __builtin_amdgcn_mfma_f32_16x16x32_bf16(
                        (p == 0) ? ax[rt] : ag[rt], bw, acc[p][rt][c], 0, 0, 0);
                }
            }
        }
    }

    // ---- epilogue (fp32); deg comes from LDS (e1-e0), no global reads ----
#pragma unroll
    for (int rt = 0; rt < 4; ++rt) {
#pragma unroll
        for (int i = 0; i < 4; ++i) {
            int lrow = rt * 16 + quad * 4 + i;
            int row = row0 + lrow;
            if (row < M) {
                float dg = sdeg[lrow];
#pragma unroll
                for (int c = 0; c < 2; ++c) {
                    int col = wave * 32 + c * 16 + ln;
                    float p1 = acc[0][rt][c][i] + B1[col];
                    float h2 = 2.f * (acc[1][rt][c][i] + dg * B2[col]);
                    float z  = 2.f * (acc[2][rt][c][i] + dg * (B3[col] + B4[col]));
                    float g = 1.f / (1.f + __expf(-z));
                    out[(size_t)row * 128 + col] = g * h2 + p1;
                }
            }
        }
    }
}

extern "C" void kernel_launch(void* const* d_in, const int* in_sizes, int n_in,
                              void* d_out, int out_size, void* d_ws, size_t ws_size,
                              hipStream_t stream) {
    const float* x  = (const float*)d_in[0];
    const int* eidx = (const int*)d_in[1];
    const float* W1 = (const float*)d_in[2];
    const float* B1 = (const float*)d_in[3];
    const float* W2 = (const float*)d_in[4];
    const float* B2 = (const float*)d_in[5];
    const float* W3 = (const float*)d_in[6];
    const float* B3 = (const float*)d_in[7];
    const float* W4 = (const float*)d_in[8];
    const float* B4 = (const float*)d_in[9];
    float* out      = (float*)d_out;

    const int M  = in_sizes[0] / 128;   // 100000 nodes
    const int NE = in_sizes[1] / 2;     // 1600000 edges
    const int* src = eidx;
    const int* dst = eidx + NE;

    const int NB = (M + BRANGE - 1) >> BSHIFT;   // buckets (196 for M=100000)

    auto pad = [](size_t b) { return (b + 127) & ~(size_t)127; };
    const size_t xb_bytes  = pad((size_t)M * 128 * 2);
    const size_t wb_bytes  = pad((size_t)3 * 16384 * 2);
    const size_t deg_bytes = pad((size_t)M * 4);
    const size_t off_bytes = pad((size_t)(M + 1) * 4);
    const size_t csr_bytes = pad((size_t)NE * 4);
    const size_t bkt_bytes = pad((size_t)NE * 8);

    const size_t need_full = xb_bytes + wb_bytes + deg_bytes + off_bytes +
                             1024 + csr_bytes + bkt_bytes + 4 * 1024;
    const bool full = (NB <= 256) && ws_size >= need_full + 1024;

    char* ws = (char*)d_ws;
    size_t off = 0;
    auto take = [&](size_t bytes) -> char* {
        char* p = ws + off;
        off = (off + bytes + 127) & ~(size_t)127;
        return p;
    };

    const int nbScan = (M + 1023) / 1024;

    if (full) {
        unsigned short* xb = (unsigned short*)take(xb_bytes);
        unsigned short* Wb = (unsigned short*)take(wb_bytes);
        int* deg   = (int*)take((size_t)M * 4);
        int* offs  = (int*)take((size_t)(M + 1) * 4);
        int* bsum  = (int*)take(256 * 4);
        int* csr   = (int*)take((size_t)NE * 4);
        int2* bkt  = (int2*)take((size_t)NE * 8);
        int* bcnt  = (int*)take(256 * 4);
        int* boff  = (int*)take(257 * 4);
        int* gcur  = (int*)take(256 * 4);

        const int nx4 = M * 128 / 4;
        const int chunk = (NE + 255) / 256;

        prep_kernel<<<(M * 32 + 255) / 256, 256, 0, stream>>>(
            x, W1, W2, W3, W4, xb, Wb, deg, bcnt, M, nx4);
        bucket_hist_kernel<<<256, 512, 0, stream>>>(dst, bcnt, NE, NB);
        bucket_scan_kernel<<<1, 256, 0, stream>>>(bcnt, boff, gcur, NB);
        bucketize_kernel<<<256, 512, 0, stream>>>(src, dst, gcur, bkt, NE, chunk);
        bucket_count_kernel<<<NB, 512, 0, stream>>>(bkt, boff, deg, M);
        scan_local_kernel<<<nbScan, 1024, 0, stream>>>(deg, offs, bsum, M);
        scan_totals_kernel<<<1, 128, 0, stream>>>(bsum, offs, nbScan, M);
        scan_finalize_kernel<<<nbScan, 1024, 0, stream>>>(offs, bsum, nullptr, M);
        bucket_fill_kernel<<<NB, 512, 0, stream>>>(bkt, boff, offs, csr, M);
        fused_gather_gemm_kernel<true><<<(M + 63) / 64, 256, 0, stream>>>(
            xb, offs, csr, Wb, B1, B2, B3, B4, out, M);
    } else {
        // low-workspace fallback: fp32 fused kernel + atomic hist + ranged fill
        unsigned short* Wb = (unsigned short*)take(wb_bytes);
        int* deg    = (int*)take((size_t)M * 4);
        int* offs   = (int*)take((size_t)(M + 1) * 4);
        int* cursor = (int*)take((size_t)M * 4);
        int* bsum   = (int*)take(256 * 4);
        int* csr    = (int*)take((size_t)NE * 4);
        unsigned short* xb_unused = nullptr; (void)xb_unused;

        const int prep_elems = (M > 16384 ? M : 16384);
        const int rangeSize = (M + 7) / 8;
        prep_kernel<<<(prep_elems + 255) / 256, 256, 0, stream>>>(
            x, W1, W2, W3, W4, nullptr, Wb, deg, nullptr, M, 0);
        hist_kernel<<<(NE + 255) / 256, 256, 0, stream>>>(dst, deg, NE);
        scan_local_kernel<<<nbScan, 1024, 0, stream>>>(deg, offs, bsum, M);
        scan_totals_kernel<<<1, 128, 0, stream>>>(bsum, offs, nbScan, M);
        scan_finalize_kernel<<<nbScan, 1024, 0, stream>>>(offs, bsum, cursor, M);
        fill_csr_ranged_kernel<<<2048, 256, 0, stream>>>(src, dst, cursor, csr, NE, rangeSize);
        fused_gather_gemm_kernel<false><<<(M + 63) / 64, 256, 0, stream>>>(
            x, offs, csr, Wb, B1, B2, B3, B4, out, M);
    }
}

// Round 7
// 289.093 us; speedup vs baseline: 1.2788x; 1.2788x over previous
//
#include <hip/hip_runtime.h>

// ---------- fp32 <-> bf16 helpers ----------
__device__ __forceinline__ float bf2f(unsigned short u) {
    union { unsigned int i; float f; } v;
    v.i = ((unsigned int)u) << 16;
    return v.f;
}
__device__ __forceinline__ unsigned short f2bf(float f) {
    union { float f; unsigned int i; } v;
    v.f = f;
    unsigned int x = v.i;
    return (unsigned short)((x + 0x7fffu + ((x >> 16) & 1u)) >> 16);
}

typedef short bf16x8 __attribute__((ext_vector_type(8)));
typedef float f32x4 __attribute__((ext_vector_type(4)));

// bucket geometry: 512 nodes per bucket (shift 9); NB = ceil(M/512) <= 256
#define BSHIFT 9
#define BRANGE 512

// ---------- prep: zero deg+bcnt, x fp32->bf16, W panels -> bf16 ----------
__global__ void prep_kernel(const float* __restrict__ x,
                            const float* __restrict__ W1, const float* __restrict__ W2,
                            const float* __restrict__ W3, const float* __restrict__ W4,
                            unsigned short* __restrict__ xb, unsigned short* __restrict__ Wb,
                            int* __restrict__ deg, int* __restrict__ bcnt, int M, int nx4)
{
    int i = blockIdx.x * 256 + threadIdx.x;
    if (i < nx4) {
        float4 v = ((const float4*)x)[i];
        unsigned lo = (unsigned)f2bf(v.x) | ((unsigned)f2bf(v.y) << 16);
        unsigned hi = (unsigned)f2bf(v.z) | ((unsigned)f2bf(v.w) << 16);
        uint2 p; p.x = lo; p.y = hi;
        *(uint2*)(xb + (size_t)i * 4) = p;
    }
    if (deg && i < M) deg[i] = 0;
    if (bcnt && i < 256) bcnt[i] = 0;
    if (i < 16384) {
        Wb[i]         = f2bf(W1[i]);
        Wb[16384 + i] = f2bf(W2[i]);
        Wb[32768 + i] = f2bf(W3[i] + W4[i]);
    }
}

// ---------- bucketed CSR build (atomic-poor), proven in round-3 bench ----------
__global__ __launch_bounds__(512) void bucket_hist_kernel(
    const int* __restrict__ dst, int* __restrict__ bcnt, int ne, int nb)
{
    __shared__ int h[256];
    int t = threadIdx.x;
    if (t < 256) h[t] = 0;
    __syncthreads();
    for (int i = blockIdx.x * 512 + t; i < ne; i += gridDim.x * 512)
        atomicAdd(&h[dst[i] >> BSHIFT], 1);
    __syncthreads();
    if (t < nb) {
        int c = h[t];
        if (c) atomicAdd(&bcnt[t], c);
    }
}

__global__ __launch_bounds__(256) void bucket_scan_kernel(
    const int* __restrict__ bcnt, int* __restrict__ boff, int* __restrict__ gcur, int nb)
{
    __shared__ int sh[256];
    int t = threadIdx.x;
    int v = (t < nb) ? bcnt[t] : 0;
    sh[t] = v;
    __syncthreads();
    int acc = v;
    for (int off = 1; off < 256; off <<= 1) {
        int y = (t >= off) ? sh[t - off] : 0;
        __syncthreads();
        acc += y;
        sh[t] = acc;
        __syncthreads();
    }
    if (t < nb) {
        boff[t + 1] = acc;        // inclusive
        gcur[t] = acc - v;        // exclusive: region cursor
    }
    if (t == 0) boff[0] = 0;
}

// Partition edges into dst-range buckets. Per block: LDS count pass, ONE global
// atomic per touched bucket to claim a contiguous run, then LDS-cursor scatter.
__global__ __launch_bounds__(512) void bucketize_kernel(
    const int* __restrict__ src, const int* __restrict__ dst,
    int* __restrict__ gcur, int2* __restrict__ bucketed, int ne, int chunk)
{
    __shared__ int cnt[256];
    __shared__ int sbase[256];
    const int t = threadIdx.x;
    const int e0 = blockIdx.x * chunk;
    const int e1 = (e0 + chunk < ne) ? e0 + chunk : ne;

    if (t < 256) cnt[t] = 0;
    __syncthreads();
    for (int e = e0 + t; e < e1; e += 512)
        atomicAdd(&cnt[dst[e] >> BSHIFT], 1);
    __syncthreads();
    if (t < 256) {
        int c = cnt[t];
        sbase[t] = c ? atomicAdd(&gcur[t], c) : 0;
        cnt[t] = 0;
    }
    __syncthreads();
    for (int e = e0 + t; e < e1; e += 512) {
        int d = dst[e];
        int b = d >> BSHIFT;
        int loc = atomicAdd(&cnt[b], 1);
        int2 v; v.x = src[e]; v.y = d;
        bucketed[sbase[b] + loc] = v;
    }
}

// one block per bucket: LDS histogram over the bucket's 512-node range -> deg
__global__ __launch_bounds__(512) void bucket_count_kernel(
    const int2* __restrict__ bucketed, const int* __restrict__ boff,
    int* __restrict__ deg, int M)
{
    __shared__ int cnt[BRANGE];
    const int t = threadIdx.x;
    const int b = blockIdx.x;
    cnt[t] = 0;
    __syncthreads();
    const int lo = boff[b], hi = boff[b + 1];
    for (int i = lo + t; i < hi; i += 512)
        atomicAdd(&cnt[bucketed[i].y & (BRANGE - 1)], 1);
    __syncthreads();
    int node = (b << BSHIFT) + t;
    if (node < M) deg[node] = cnt[t];
}

// one block per bucket: LDS cursors seeded from offs, plain csr stores.
__global__ __launch_bounds__(512) void bucket_fill_kernel(
    const int2* __restrict__ bucketed, const int* __restrict__ boff,
    const int* __restrict__ offs, int* __restrict__ csr, int M)
{
    __shared__ int cur[BRANGE];
    const int t = threadIdx.x;
    const int b = blockIdx.x;
    int node = (b << BSHIFT) + t;
    cur[t] = (node < M) ? offs[node] : 0;
    __syncthreads();
    const int lo = boff[b], hi = boff[b + 1];
    for (int i = lo + t; i < hi; i += 512) {
        int2 e = bucketed[i];
        int p = atomicAdd(&cur[e.y & (BRANGE - 1)], 1);
        csr[p] = e.x;
    }
}

// ---------- fallback-path CSR build (atomic histogram + global scan + ranged fill) ----------
__global__ void hist_kernel(const int* __restrict__ dst, int* __restrict__ deg, int ne) {
    int e = blockIdx.x * blockDim.x + threadIdx.x;
    if (e < ne) atomicAdd(&deg[dst[e]], 1);
}

__global__ __launch_bounds__(1024) void scan_local_kernel(
    const int* __restrict__ deg, int* __restrict__ offs, int* __restrict__ bsum, int n)
{
    __shared__ int sh[1024];
    int t = threadIdx.x;
    int i = blockIdx.x * 1024 + t;
    int v = (i < n) ? deg[i] : 0;
    sh[t] = v;
    __syncthreads();
    int acc = v;
    for (int off = 1; off < 1024; off <<= 1) {
        int y = (t >= off) ? sh[t - off] : 0;
        __syncthreads();
        acc += y;
        sh[t] = acc;
        __syncthreads();
    }
    if (i < n) offs[i] = acc - v;  // exclusive within block
    if (t == 1023) bsum[blockIdx.x] = acc;
}

__global__ __launch_bounds__(128) void scan_totals_kernel(
    int* __restrict__ bsum, int* __restrict__ offs, int nb, int n)
{
    __shared__ int sh[128];
    int t = threadIdx.x;
    int v = (t < nb) ? bsum[t] : 0;
    sh[t] = v;
    __syncthreads();
    int acc = v;
    for (int off = 1; off < 128; off <<= 1) {
        int y = (t >= off) ? sh[t - off] : 0;
        __syncthreads();
        acc += y;
        sh[t] = acc;
        __syncthreads();
    }
    if (t < nb) bsum[t] = acc - v;   // exclusive block offsets, in place
    if (t == 127) offs[n] = acc;     // grand total == NE
}

__global__ __launch_bounds__(1024) void scan_finalize_kernel(
    int* __restrict__ offs, const int* __restrict__ bsum, int* __restrict__ cursor, int n)
{
    int i = blockIdx.x * 1024 + threadIdx.x;
    if (i < n) {
        int o = offs[i] + bsum[i >> 10];
        offs[i] = o;
        if (cursor) cursor[i] = o;
    }
}

__global__ __launch_bounds__(256) void fill_csr_ranged_kernel(
    const int* __restrict__ src, const int* __restrict__ dst,
    int* __restrict__ cursor, int* __restrict__ csr, int ne, int rangeSize)
{
    const int r = blockIdx.x & 7;
    const int cb = blockIdx.x >> 3;
    const int nchunk = gridDim.x >> 3;
    const unsigned lo = (unsigned)(r * rangeSize);
    for (int e = cb * 256 + threadIdx.x; e < ne; e += nchunk * 256) {
        int d = dst[e];
        int s = src[e];
        if ((unsigned)(d - lo) < (unsigned)rangeSize) {
            int pos = atomicAdd(&cursor[d], 1);
            csr[pos] = s;
        }
    }
}

// ---------- gather: one wave per node, 8-deep masked unroll, bf16 out ----------
template<bool BF16SRC>
__global__ __launch_bounds__(256) void gather_kernel(
    const void* __restrict__ xsrc, const int* __restrict__ offs,
    const int* __restrict__ csr, unsigned short* __restrict__ gb, int M)
{
    const int wave = threadIdx.x >> 6;
    const int lane = threadIdx.x & 63;
    const int node = blockIdx.x * 4 + wave;
    if (node >= M) return;
    const int e0 = offs[node];
    const int e1 = offs[node + 1];

    float s0 = 0.f, s1 = 0.f, t0 = 0.f, t1 = 0.f;
    for (int e = e0; e < e1; e += 8) {
        int id[8];
        float m[8];
#pragma unroll
        for (int j = 0; j < 8; ++j) {
            int ee = e + j;
            bool ok = ee < e1;
            id[j] = csr[ok ? ee : e1 - 1];
            m[j] = ok ? 1.f : 0.f;
        }
#pragma unroll
        for (int j = 0; j < 8; ++j) {
            float lo, hi;
            if (BF16SRC) {
                unsigned v = *(const unsigned*)((const unsigned short*)xsrc +
                                                (size_t)id[j] * 128 + lane * 2);
                lo = bf2f((unsigned short)(v & 0xffffu));
                hi = bf2f((unsigned short)(v >> 16));
            } else {
                float2 v = *(const float2*)((const float*)xsrc +
                                            (size_t)id[j] * 128 + lane * 2);
                lo = v.x;
                hi = v.y;
            }
            if (j & 1) { t0 += m[j] * lo; t1 += m[j] * hi; }
            else       { s0 += m[j] * lo; s1 += m[j] * hi; }
        }
    }
    unsigned pk = (unsigned)f2bf(s0 + t0) | ((unsigned)f2bf(s1 + t1) << 16);
    *(unsigned*)(gb + (size_t)node * 128 + lane * 2) = pk;
}

// ---------- 3-panel bf16 MFMA GEMM + fp32 epilogue, 32-row tile ----------
// 32-row tile halves LDS (17.4 KB) and accumulators vs the 64-row version:
// ~8 blocks/CU instead of 4 -> 2x latency hiding for the stage->MFMA->store chain.
// P1 = x*W1^T ; P2 = g*W2^T ; P34 = g*(W3+W4)^T
// out = sigmoid(2*(P34 + d*(b3+b4))) * (2*(P2 + d*b2)) + P1 + b1
template<bool XBF16>
__global__ __launch_bounds__(256) void gemm_kernel(
    const void* __restrict__ xsrc, const unsigned short* __restrict__ gb,
    const int* __restrict__ deg, const unsigned short* __restrict__ Wb,
    const float* __restrict__ B1, const float* __restrict__ B2,
    const float* __restrict__ B3, const float* __restrict__ B4,
    float* __restrict__ out, int M)
{
    __shared__ unsigned short x_lds[32 * 136];
    __shared__ unsigned short g_lds[32 * 136];

    const int t = threadIdx.x;
    const int wave = t >> 6;
    const int lane = t & 63;
    const int ln = lane & 15;
    const int quad = lane >> 4;
    const int row0 = blockIdx.x * 32;

    // ---- stage x tile (32 rows x 128 bf16) ----
    if (XBF16) {
        const unsigned short* xb = (const unsigned short*)xsrc;
#pragma unroll
        for (int i = 0; i < 2; ++i) {
            int c = i * 256 + t;          // 512 chunks of 16B
            int row = c >> 4;
            int koff = (c & 15) * 8;
            int grow = row0 + row;
            if (grow > M - 1) grow = M - 1;
            *(uint4*)&x_lds[row * 136 + koff] =
                *(const uint4*)(xb + (size_t)grow * 128 + koff);
        }
    } else {
        const float* xf = (const float*)xsrc;
#pragma unroll
        for (int i = 0; i < 4; ++i) {
            int c = i * 256 + t;          // 1024 chunks of float4
            int row = c >> 5;
            int koff = (c & 31) * 4;
            int grow = row0 + row;
            if (grow > M - 1) grow = M - 1;
            float4 v = *(const float4*)(xf + (size_t)grow * 128 + koff);
            unsigned p0 = (unsigned)f2bf(v.x) | ((unsigned)f2bf(v.y) << 16);
            unsigned p1 = (unsigned)f2bf(v.z) | ((unsigned)f2bf(v.w) << 16);
            *(unsigned*)&x_lds[row * 136 + koff]     = p0;
            *(unsigned*)&x_lds[row * 136 + koff + 2] = p1;
        }
    }
    // ---- stage g tile ----
#pragma unroll
    for (int i = 0; i < 2; ++i) {
        int c = i * 256 + t;
        int row = c >> 4;
        int koff = (c & 15) * 8;
        int grow = row0 + row;
        if (grow > M - 1) grow = M - 1;
        *(uint4*)&g_lds[row * 136 + koff] =
            *(const uint4*)(gb + (size_t)grow * 128 + koff);
    }
    __syncthreads();

    // ---- 3-panel GEMM: wave owns cols [wave*32, wave*32+32), rows 0..31 ----
    f32x4 acc[3][2][2];
#pragma unroll
    for (int p = 0; p < 3; ++p)
#pragma unroll
        for (int rt = 0; rt < 2; ++rt)
#pragma unroll
            for (int c = 0; c < 2; ++c) {
                acc[p][rt][c][0] = 0.f; acc[p][rt][c][1] = 0.f;
                acc[p][rt][c][2] = 0.f; acc[p][rt][c][3] = 0.f;
            }

#pragma unroll
    for (int kk = 0; kk < 4; ++kk) {
        bf16x8 ax[2], ag[2];
#pragma unroll
        for (int rt = 0; rt < 2; ++rt) {
            ax[rt] = *(const bf16x8*)&x_lds[(rt * 16 + ln) * 136 + kk * 32 + quad * 8];
            ag[rt] = *(const bf16x8*)&g_lds[(rt * 16 + ln) * 136 + kk * 32 + quad * 8];
        }
#pragma unroll
        for (int p = 0; p < 3; ++p) {
#pragma unroll
            for (int c = 0; c < 2; ++c) {
                int col = wave * 32 + c * 16 + ln;
                bf16x8 bw = *(const bf16x8*)(Wb + (size_t)p * 16384 +
                                             (size_t)col * 128 + kk * 32 + quad * 8);
#pragma unroll
                for (int rt = 0; rt < 2; ++rt) {
                    acc[p][rt][c] = __builtin_amdgcn_mfma_f32_16x16x32_bf16(
                        (p == 0) ? ax[rt] : ag[rt], bw, acc[p][rt][c], 0, 0, 0);
                }
            }
        }
    }

    // ---- epilogue (fp32) ----
#pragma unroll
    for (int rt = 0; rt < 2; ++rt) {
#pragma unroll
        for (int i = 0; i < 4; ++i) {
            int row = row0 + rt * 16 + quad * 4 + i;
            if (row < M) {
                float dg = (float)deg[row];
#pragma unroll
                for (int c = 0; c < 2; ++c) {
                    int col = wave * 32 + c * 16 + ln;
                    float p1 = acc[0][rt][c][i] + B1[col];
                    float h2 = 2.f * (acc[1][rt][c][i] + dg * B2[col]);
                    float z  = 2.f * (acc[2][rt][c][i] + dg * (B3[col] + B4[col]));
                    float g = 1.f / (1.f + __expf(-z));
                    out[(size_t)row * 128 + col] = g * h2 + p1;
                }
            }
        }
    }
}

extern "C" void kernel_launch(void* const* d_in, const int* in_sizes, int n_in,
                              void* d_out, int out_size, void* d_ws, size_t ws_size,
                              hipStream_t stream) {
    const float* x  = (const float*)d_in[0];
    const int* eidx = (const int*)d_in[1];
    const float* W1 = (const float*)d_in[2];
    const float* B1 = (const float*)d_in[3];
    const float* W2 = (const float*)d_in[4];
    const float* B2 = (const float*)d_in[5];
    const float* W3 = (const float*)d_in[6];
    const float* B3 = (const float*)d_in[7];
    const float* W4 = (const float*)d_in[8];
    const float* B4 = (const float*)d_in[9];
    float* out      = (float*)d_out;

    const int M  = in_sizes[0] / 128;   // 100000 nodes
    const int NE = in_sizes[1] / 2;     // 1600000 edges
    const int* src = eidx;
    const int* dst = eidx + NE;

    const int NB = (M + BRANGE - 1) >> BSHIFT;   // buckets (196 for M=100000)

    auto pad = [](size_t b) { return (b + 127) & ~(size_t)127; };
    const size_t xb_bytes  = pad((size_t)M * 128 * 2);
    const size_t gb_bytes  = pad((size_t)M * 128 * 2);
    const size_t wb_bytes  = pad((size_t)3 * 16384 * 2);
    const size_t deg_bytes = pad((size_t)M * 4);
    const size_t off_bytes = pad((size_t)(M + 1) * 4);
    const size_t csr_bytes = pad((size_t)NE * 4);
    const size_t bkt_bytes = pad((size_t)NE * 8);

    const size_t need_full = xb_bytes + gb_bytes + wb_bytes + deg_bytes + off_bytes +
                             1024 + csr_bytes + bkt_bytes + 4 * 1024;
    const bool full = (NB <= 256) && ws_size >= need_full + 1024;

    char* ws = (char*)d_ws;
    size_t off = 0;
    auto take = [&](size_t bytes) -> char* {
        char* p = ws + off;
        off = (off + bytes + 127) & ~(size_t)127;
        return p;
    };

    const int nbScan = (M + 1023) / 1024;

    if (full) {
        unsigned short* xb = (unsigned short*)take(xb_bytes);
        unsigned short* gb = (unsigned short*)take(gb_bytes);
        unsigned short* Wb = (unsigned short*)take(wb_bytes);
        int* deg   = (int*)take((size_t)M * 4);
        int* offs  = (int*)take((size_t)(M + 1) * 4);
        int* bsum  = (int*)take(256 * 4);
        int* csr   = (int*)take((size_t)NE * 4);
        int2* bkt  = (int2*)take((size_t)NE * 8);
        int* bcnt  = (int*)take(256 * 4);
        int* boff  = (int*)take(257 * 4);
        int* gcur  = (int*)take(256 * 4);

        const int nx4 = M * 128 / 4;
        const int chunk = (NE + 255) / 256;

        prep_kernel<<<(M * 32 + 255) / 256, 256, 0, stream>>>(
            x, W1, W2, W3, W4, xb, Wb, deg, bcnt, M, nx4);
        bucket_hist_kernel<<<256, 512, 0, stream>>>(dst, bcnt, NE, NB);
        bucket_scan_kernel<<<1, 256, 0, stream>>>(bcnt, boff, gcur, NB);
        bucketize_kernel<<<256, 512, 0, stream>>>(src, dst, gcur, bkt, NE, chunk);
        bucket_count_kernel<<<NB, 512, 0, stream>>>(bkt, boff, deg, M);
        scan_local_kernel<<<nbScan, 1024, 0, stream>>>(deg, offs, bsum, M);
        scan_totals_kernel<<<1, 128, 0, stream>>>(bsum, offs, nbScan, M);
        scan_finalize_kernel<<<nbScan, 1024, 0, stream>>>(offs, bsum, nullptr, M);
        bucket_fill_kernel<<<NB, 512, 0, stream>>>(bkt, boff, offs, csr, M);
        gather_kernel<true><<<(M + 3) / 4, 256, 0, stream>>>(xb, offs, csr, gb, M);
        gemm_kernel<true><<<(M + 31) / 32, 256, 0, stream>>>(
            xb, gb, deg, Wb, B1, B2, B3, B4, out, M);
    } else {
        // low-workspace fallback: fp32 gather + atomic hist + global scan + ranged fill
        unsigned short* gb = (unsigned short*)take(gb_bytes);
        unsigned short* Wb = (unsigned short*)take(wb_bytes);
        int* deg    = (int*)take((size_t)M * 4);
        int* offs   = (int*)take((size_t)(M + 1) * 4);
        int* cursor = (int*)take((size_t)M * 4);
        int* bsum   = (int*)take(256 * 4);
        int* csr    = (int*)take((size_t)NE * 4);

        const int prep_elems = (M > 16384 ? M : 16384);
        const int rangeSize = (M + 7) / 8;
        prep_kernel<<<(prep_elems + 255) / 256, 256, 0, stream>>>(
            x, W1, W2, W3, W4, nullptr, Wb, deg, nullptr, M, 0);
        hist_kernel<<<(NE + 255) / 256, 256, 0, stream>>>(dst, deg, NE);
        scan_local_kernel<<<nbScan, 1024, 0, stream>>>(deg, offs, bsum, M);
        scan_totals_kernel<<<1, 128, 0, stream>>>(bsum, offs, nbScan, M);
        scan_finalize_kernel<<<nbScan, 1024, 0, stream>>>(offs, bsum, cursor, M);
        fill_csr_ranged_kernel<<<2048, 256, 0, stream>>>(src, dst, cursor, csr, NE, rangeSize);
        gather_kernel<false><<<(M + 3) / 4, 256, 0, stream>>>(x, offs, csr, gb, M);
        gemm_kernel<false><<<(M + 31) / 32, 256, 0, stream>>>(
            x, gb, deg, Wb, B1, B2, B3, B4, out, M);
    }
}

// Round 8
// 282.056 us; speedup vs baseline: 1.3107x; 1.0249x over previous
//
#include <hip/hip_runtime.h>

// ---------- fp32 <-> bf16 helpers ----------
__device__ __forceinline__ float bf2f(unsigned short u) {
    union { unsigned int i; float f; } v;
    v.i = ((unsigned int)u) << 16;
    return v.f;
}
__device__ __forceinline__ unsigned short f2bf(float f) {
    union { float f; unsigned int i; } v;
    v.f = f;
    unsigned int x = v.i;
    return (unsigned short)((x + 0x7fffu + ((x >> 16) & 1u)) >> 16);
}

typedef short bf16x8 __attribute__((ext_vector_type(8)));
typedef float f32x4 __attribute__((ext_vector_type(4)));

// bucket geometry: 512 nodes per bucket (shift 9); NB = ceil(M/512) <= 256
#define BSHIFT 9
#define BRANGE 512

// ---------- merged prep + bucket-histogram ----------
// All blocks: x fp32->bf16 and W panels -> bf16. Blocks 0..255 additionally build
// a per-block partial bucket histogram over a strided edge slice and write it to
// bpart[blk][0..255] with PLAIN stores (no global zero-init needed, no races).
// deg is NOT zeroed here: bucket_finalize writes every deg entry with plain stores.
__global__ __launch_bounds__(256) void prep_hist_kernel(
    const float* __restrict__ x,
    const float* __restrict__ W1, const float* __restrict__ W2,
    const float* __restrict__ W3, const float* __restrict__ W4,
    unsigned short* __restrict__ xb, unsigned short* __restrict__ Wb,
    const int* __restrict__ dst, int* __restrict__ bpart,
    int M, int nx4, int ne)
{
    __shared__ int h[256];
    const int t = threadIdx.x;
    const int blk = blockIdx.x;
    const bool histBlock = (blk < 256);
    if (histBlock) {               // block-uniform branch: barrier is safe
        h[t] = 0;
        __syncthreads();
    }

    int i = blk * 256 + t;
    if (i < nx4) {
        float4 v = ((const float4*)x)[i];
        unsigned lo = (unsigned)f2bf(v.x) | ((unsigned)f2bf(v.y) << 16);
        unsigned hi = (unsigned)f2bf(v.z) | ((unsigned)f2bf(v.w) << 16);
        uint2 p; p.x = lo; p.y = hi;
        *(uint2*)(xb + (size_t)i * 4) = p;
    }
    if (i < 16384) {
        Wb[i]         = f2bf(W1[i]);
        Wb[16384 + i] = f2bf(W2[i]);
        Wb[32768 + i] = f2bf(W3[i] + W4[i]);
    }

    if (histBlock) {
        for (int e = blk * 256 + t; e < ne; e += 65536)
            atomicAdd(&h[dst[e] >> BSHIFT], 1);
        __syncthreads();
        bpart[blk * 256 + t] = h[t];   // plain store, fully overwritten
    }
}

// single block: reduce 256 partial histograms -> bucket counts -> scan ->
// boff[0..nb] (bucket offsets) and gcur (region cursors for bucketize)
__global__ __launch_bounds__(256) void bucket_scan_kernel(
    const int* __restrict__ bpart, int* __restrict__ boff, int* __restrict__ gcur, int nb)
{
    __shared__ int sh[256];
    int t = threadIdx.x;
    int v = 0;
    for (int k = 0; k < 256; ++k) v += bpart[k * 256 + t];   // coalesced per k
    if (t >= nb) v = 0;
    sh[t] = v;
    __syncthreads();
    int acc = v;
    for (int off = 1; off < 256; off <<= 1) {
        int y = (t >= off) ? sh[t - off] : 0;
        __syncthreads();
        acc += y;
        sh[t] = acc;
        __syncthreads();
    }
    if (t < nb) {
        boff[t + 1] = acc;        // inclusive
        gcur[t] = acc - v;        // exclusive: region cursor
    }
    if (t == 0) boff[0] = 0;
}

// Partition edges into dst-range buckets. Per block: LDS count pass, ONE global
// atomic per touched bucket to claim a contiguous run, then LDS-cursor scatter.
__global__ __launch_bounds__(512) void bucketize_kernel(
    const int* __restrict__ src, const int* __restrict__ dst,
    int* __restrict__ gcur, int2* __restrict__ bucketed, int ne, int chunk)
{
    __shared__ int cnt[256];
    __shared__ int sbase[256];
    const int t = threadIdx.x;
    const int e0 = blockIdx.x * chunk;
    const int e1 = (e0 + chunk < ne) ? e0 + chunk : ne;

    if (t < 256) cnt[t] = 0;
    __syncthreads();
    for (int e = e0 + t; e < e1; e += 512)
        atomicAdd(&cnt[dst[e] >> BSHIFT], 1);
    __syncthreads();
    if (t < 256) {
        int c = cnt[t];
        sbase[t] = c ? atomicAdd(&gcur[t], c) : 0;
        cnt[t] = 0;
    }
    __syncthreads();
    for (int e = e0 + t; e < e1; e += 512) {
        int d = dst[e];
        int b = d >> BSHIFT;
        int loc = atomicAdd(&cnt[b], 1);
        int2 v; v.x = src[e]; v.y = d;
        bucketed[sbase[b] + loc] = v;
    }
}

// ---------- merged finalize: per-bucket hist -> LDS scan -> offs/deg -> csr fill ----------
// csr is bucket-major contiguous, so offs[node] = boff[b] + (exclusive prefix of
// counts within the bucket). Replaces bucket_count + 3 global-scan kernels +
// bucket_fill (5 launches -> 1).
__global__ __launch_bounds__(512) void bucket_finalize_kernel(
    const int2* __restrict__ bucketed, const int* __restrict__ boff,
    int* __restrict__ offs, int* __restrict__ deg, int* __restrict__ csr,
    int M, int nb)
{
    __shared__ int cnt[BRANGE];
    __shared__ int sc[BRANGE];
    const int t = threadIdx.x;
    const int b = blockIdx.x;
    cnt[t] = 0;
    __syncthreads();
    const int lo = boff[b], hi = boff[b + 1];
    for (int i = lo + t; i < hi; i += 512)
        atomicAdd(&cnt[bucketed[i].y & (BRANGE - 1)], 1);
    __syncthreads();
    const int v = cnt[t];
    // Hillis-Steele inclusive scan over 512
    sc[t] = v;
    __syncthreads();
    int acc = v;
    for (int off = 1; off < 512; off <<= 1) {
        int y = (t >= off) ? sc[t - off] : 0;
        __syncthreads();
        acc += y;
        sc[t] = acc;
        __syncthreads();
    }
    const int excl = acc - v;
    const int node = (b << BSHIFT) + t;
    if (node < M) {
        offs[node] = lo + excl;
        deg[node] = v;
    }
    if (b == nb - 1 && t == 0) offs[M] = hi;   // grand total == NE
    // reuse cnt[] as cursors
    cnt[t] = lo + excl;
    __syncthreads();
    for (int i = lo + t; i < hi; i += 512) {
        int2 e = bucketed[i];
        int p = atomicAdd(&cnt[e.y & (BRANGE - 1)], 1);
        csr[p] = e.x;
    }
}

// ---------- fallback-path kernels (low workspace), proven ----------
__global__ void prep_kernel(const float* __restrict__ x,
                            const float* __restrict__ W1, const float* __restrict__ W2,
                            const float* __restrict__ W3, const float* __restrict__ W4,
                            unsigned short* __restrict__ xb, unsigned short* __restrict__ Wb,
                            int* __restrict__ deg, int M, int nx4)
{
    int i = blockIdx.x * 256 + threadIdx.x;
    if (i < nx4) {
        float4 v = ((const float4*)x)[i];
        unsigned lo = (unsigned)f2bf(v.x) | ((unsigned)f2bf(v.y) << 16);
        unsigned hi = (unsigned)f2bf(v.z) | ((unsigned)f2bf(v.w) << 16);
        uint2 p; p.x = lo; p.y = hi;
        *(uint2*)(xb + (size_t)i * 4) = p;
    }
    if (deg && i < M) deg[i] = 0;
    if (i < 16384) {
        Wb[i]         = f2bf(W1[i]);
        Wb[16384 + i] = f2bf(W2[i]);
        Wb[32768 + i] = f2bf(W3[i] + W4[i]);
    }
}

__global__ void hist_kernel(const int* __restrict__ dst, int* __restrict__ deg, int ne) {
    int e = blockIdx.x * blockDim.x + threadIdx.x;
    if (e < ne) atomicAdd(&deg[dst[e]], 1);
}

__global__ __launch_bounds__(1024) void scan_local_kernel(
    const int* __restrict__ deg, int* __restrict__ offs, int* __restrict__ bsum, int n)
{
    __shared__ int sh[1024];
    int t = threadIdx.x;
    int i = blockIdx.x * 1024 + t;
    int v = (i < n) ? deg[i] : 0;
    sh[t] = v;
    __syncthreads();
    int acc = v;
    for (int off = 1; off < 1024; off <<= 1) {
        int y = (t >= off) ? sh[t - off] : 0;
        __syncthreads();
        acc += y;
        sh[t] = acc;
        __syncthreads();
    }
    if (i < n) offs[i] = acc - v;  // exclusive within block
    if (t == 1023) bsum[blockIdx.x] = acc;
}

__global__ __launch_bounds__(128) void scan_totals_kernel(
    int* __restrict__ bsum, int* __restrict__ offs, int nb, int n)
{
    __shared__ int sh[128];
    int t = threadIdx.x;
    int v = (t < nb) ? bsum[t] : 0;
    sh[t] = v;
    __syncthreads();
    int acc = v;
    for (int off = 1; off < 128; off <<= 1) {
        int y = (t >= off) ? sh[t - off] : 0;
        __syncthreads();
        acc += y;
        sh[t] = acc;
        __syncthreads();
    }
    if (t < nb) bsum[t] = acc - v;   // exclusive block offsets, in place
    if (t == 127) offs[n] = acc;     // grand total == NE
}

__global__ __launch_bounds__(1024) void scan_finalize_kernel(
    int* __restrict__ offs, const int* __restrict__ bsum, int* __restrict__ cursor, int n)
{
    int i = blockIdx.x * 1024 + threadIdx.x;
    if (i < n) {
        int o = offs[i] + bsum[i >> 10];
        offs[i] = o;
        if (cursor) cursor[i] = o;
    }
}

__global__ __launch_bounds__(256) void fill_csr_ranged_kernel(
    const int* __restrict__ src, const int* __restrict__ dst,
    int* __restrict__ cursor, int* __restrict__ csr, int ne, int rangeSize)
{
    const int r = blockIdx.x & 7;
    const int cb = blockIdx.x >> 3;
    const int nchunk = gridDim.x >> 3;
    const unsigned lo = (unsigned)(r * rangeSize);
    for (int e = cb * 256 + threadIdx.x; e < ne; e += nchunk * 256) {
        int d = dst[e];
        int s = src[e];
        if ((unsigned)(d - lo) < (unsigned)rangeSize) {
            int pos = atomicAdd(&cursor[d], 1);
            csr[pos] = s;
        }
    }
}

// ---------- gather: one wave per node, 8-deep masked unroll, bf16 out ----------
template<bool BF16SRC>
__global__ __launch_bounds__(256) void gather_kernel(
    const void* __restrict__ xsrc, const int* __restrict__ offs,
    const int* __restrict__ csr, unsigned short* __restrict__ gb, int M)
{
    const int wave = threadIdx.x >> 6;
    const int lane = threadIdx.x & 63;
    const int node = blockIdx.x * 4 + wave;
    if (node >= M) return;
    const int e0 = offs[node];
    const int e1 = offs[node + 1];

    float s0 = 0.f, s1 = 0.f, t0 = 0.f, t1 = 0.f;
    for (int e = e0; e < e1; e += 8) {
        int id[8];
        float m[8];
#pragma unroll
        for (int j = 0; j < 8; ++j) {
            int ee = e + j;
            bool ok = ee < e1;
            id[j] = csr[ok ? ee : e1 - 1];
            m[j] = ok ? 1.f : 0.f;
        }
#pragma unroll
        for (int j = 0; j < 8; ++j) {
            float lo, hi;
            if (BF16SRC) {
                unsigned v = *(const unsigned*)((const unsigned short*)xsrc +
                                                (size_t)id[j] * 128 + lane * 2);
                lo = bf2f((unsigned short)(v & 0xffffu));
                hi = bf2f((unsigned short)(v >> 16));
            } else {
                float2 v = *(const float2*)((const float*)xsrc +
                                            (size_t)id[j] * 128 + lane * 2);
                lo = v.x;
                hi = v.y;
            }
            if (j & 1) { t0 += m[j] * lo; t1 += m[j] * hi; }
            else       { s0 += m[j] * lo; s1 += m[j] * hi; }
        }
    }
    unsigned pk = (unsigned)f2bf(s0 + t0) | ((unsigned)f2bf(s1 + t1) << 16);
    *(unsigned*)(gb + (size_t)node * 128 + lane * 2) = pk;
}

// ---------- 3-panel bf16 MFMA GEMM + fp32 epilogue, 32-row tile (proven r7) ----------
// P1 = x*W1^T ; P2 = g*W2^T ; P34 = g*(W3+W4)^T
// out = sigmoid(2*(P34 + d*(b3+b4))) * (2*(P2 + d*b2)) + P1 + b1
template<bool XBF16>
__global__ __launch_bounds__(256) void gemm_kernel(
    const void* __restrict__ xsrc, const unsigned short* __restrict__ gb,
    const int* __restrict__ deg, const unsigned short* __restrict__ Wb,
    const float* __restrict__ B1, const float* __restrict__ B2,
    const float* __restrict__ B3, const float* __restrict__ B4,
    float* __restrict__ out, int M)
{
    __shared__ unsigned short x_lds[32 * 136];
    __shared__ unsigned short g_lds[32 * 136];

    const int t = threadIdx.x;
    const int wave = t >> 6;
    const int lane = t & 63;
    const int ln = lane & 15;
    const int quad = lane >> 4;
    const int row0 = blockIdx.x * 32;

    // ---- stage x tile (32 rows x 128 bf16) ----
    if (XBF16) {
        const unsigned short* xb = (const unsigned short*)xsrc;
#pragma unroll
        for (int i = 0; i < 2; ++i) {
            int c = i * 256 + t;          // 512 chunks of 16B
            int row = c >> 4;
            int koff = (c & 15) * 8;
            int grow = row0 + row;
            if (grow > M - 1) grow = M - 1;
            *(uint4*)&x_lds[row * 136 + koff] =
                *(const uint4*)(xb + (size_t)grow * 128 + koff);
        }
    } else {
        const float* xf = (const float*)xsrc;
#pragma unroll
        for (int i = 0; i < 4; ++i) {
            int c = i * 256 + t;          // 1024 chunks of float4
            int row = c >> 5;
            int koff = (c & 31) * 4;
            int grow = row0 + row;
            if (grow > M - 1) grow = M - 1;
            float4 v = *(const float4*)(xf + (size_t)grow * 128 + koff);
            unsigned p0 = (unsigned)f2bf(v.x) | ((unsigned)f2bf(v.y) << 16);
            unsigned p1 = (unsigned)f2bf(v.z) | ((unsigned)f2bf(v.w) << 16);
            *(unsigned*)&x_lds[row * 136 + koff]     = p0;
            *(unsigned*)&x_lds[row * 136 + koff + 2] = p1;
        }
    }
    // ---- stage g tile ----
#pragma unroll
    for (int i = 0; i < 2; ++i) {
        int c = i * 256 + t;
        int row = c >> 4;
        int koff = (c & 15) * 8;
        int grow = row0 + row;
        if (grow > M - 1) grow = M - 1;
        *(uint4*)&g_lds[row * 136 + koff] =
            *(const uint4*)(gb + (size_t)grow * 128 + koff);
    }
    __syncthreads();

    // ---- 3-panel GEMM: wave owns cols [wave*32, wave*32+32), rows 0..31 ----
    f32x4 acc[3][2][2];
#pragma unroll
    for (int p = 0; p < 3; ++p)
#pragma unroll
        for (int rt = 0; rt < 2; ++rt)
#pragma unroll
            for (int c = 0; c < 2; ++c) {
                acc[p][rt][c][0] = 0.f; acc[p][rt][c][1] = 0.f;
                acc[p][rt][c][2] = 0.f; acc[p][rt][c][3] = 0.f;
            }

#pragma unroll
    for (int kk = 0; kk < 4; ++kk) {
        bf16x8 ax[2], ag[2];
#pragma unroll
        for (int rt = 0; rt < 2; ++rt) {
            ax[rt] = *(const bf16x8*)&x_lds[(rt * 16 + ln) * 136 + kk * 32 + quad * 8];
            ag[rt] = *(const bf16x8*)&g_lds[(rt * 16 + ln) * 136 + kk * 32 + quad * 8];
        }
#pragma unroll
        for (int p = 0; p < 3; ++p) {
#pragma unroll
            for (int c = 0; c < 2; ++c) {
                int col = wave * 32 + c * 16 + ln;
                bf16x8 bw = *(const bf16x8*)(Wb + (size_t)p * 16384 +
                                             (size_t)col * 128 + kk * 32 + quad * 8);
#pragma unroll
                for (int rt = 0; rt < 2; ++rt) {
                    acc[p][rt][c] = __builtin_amdgcn_mfma_f32_16x16x32_bf16(
                        (p == 0) ? ax[rt] : ag[rt], bw, acc[p][rt][c], 0, 0, 0);
                }
            }
        }
    }

    // ---- epilogue (fp32) ----
#pragma unroll
    for (int rt = 0; rt < 2; ++rt) {
#pragma unroll
        for (int i = 0; i < 4; ++i) {
            int row = row0 + rt * 16 + quad * 4 + i;
            if (row < M) {
                float dg = (float)deg[row];
#pragma unroll
                for (int c = 0; c < 2; ++c) {
                    int col = wave * 32 + c * 16 + ln;
                    float p1 = acc[0][rt][c][i] + B1[col];
                    float h2 = 2.f * (acc[1][rt][c][i] + dg * B2[col]);
                    float z  = 2.f * (acc[2][rt][c][i] + dg * (B3[col] + B4[col]));
                    float g = 1.f / (1.f + __expf(-z));
                    out[(size_t)row * 128 + col] = g * h2 + p1;
                }
            }
        }
    }
}

extern "C" void kernel_launch(void* const* d_in, const int* in_sizes, int n_in,
                              void* d_out, int out_size, void* d_ws, size_t ws_size,
                              hipStream_t stream) {
    const float* x  = (const float*)d_in[0];
    const int* eidx = (const int*)d_in[1];
    const float* W1 = (const float*)d_in[2];
    const float* B1 = (const float*)d_in[3];
    const float* W2 = (const float*)d_in[4];
    const float* B2 = (const float*)d_in[5];
    const float* W3 = (const float*)d_in[6];
    const float* B3 = (const float*)d_in[7];
    const float* W4 = (const float*)d_in[8];
    const float* B4 = (const float*)d_in[9];
    float* out      = (float*)d_out;

    const int M  = in_sizes[0] / 128;   // 100000 nodes
    const int NE = in_sizes[1] / 2;     // 1600000 edges
    const int* src = eidx;
    const int* dst = eidx + NE;

    const int NB = (M + BRANGE - 1) >> BSHIFT;   // buckets (196 for M=100000)

    auto pad = [](size_t b) { return (b + 127) & ~(size_t)127; };
    const size_t xb_bytes  = pad((size_t)M * 128 * 2);
    const size_t gb_bytes  = pad((size_t)M * 128 * 2);
    const size_t wb_bytes  = pad((size_t)3 * 16384 * 2);
    const size_t deg_bytes = pad((size_t)M * 4);
    const size_t off_bytes = pad((size_t)(M + 1) * 4);
    const size_t csr_bytes = pad((size_t)NE * 4);
    const size_t bkt_bytes = pad((size_t)NE * 8);
    const size_t bpart_bytes = pad((size_t)256 * 256 * 4);

    const size_t need_full = xb_bytes + gb_bytes + wb_bytes + deg_bytes + off_bytes +
                             csr_bytes + bkt_bytes + bpart_bytes + 4 * 1024;
    const bool full = (NB <= 256) && ws_size >= need_full + 1024;

    char* ws = (char*)d_ws;
    size_t off = 0;
    auto take = [&](size_t bytes) -> char* {
        char* p = ws + off;
        off = (off + bytes + 127) & ~(size_t)127;
        return p;
    };

    const int nbScan = (M + 1023) / 1024;

    if (full) {
        unsigned short* xb = (unsigned short*)take(xb_bytes);
        unsigned short* gb = (unsigned short*)take(gb_bytes);
        unsigned short* Wb = (unsigned short*)take(wb_bytes);
        int* deg    = (int*)take((size_t)M * 4);
        int* offs   = (int*)take((size_t)(M + 1) * 4);
        int* csr    = (int*)take((size_t)NE * 4);
        int2* bkt   = (int2*)take((size_t)NE * 8);
        int* bpart  = (int*)take((size_t)256 * 256 * 4);
        int* boff   = (int*)take(257 * 4);
        int* gcur   = (int*)take(256 * 4);

        const int nx4 = M * 128 / 4;
        const int chunk = (NE + 255) / 256;
        int prep_grid = (M * 32 + 255) / 256;
        if (prep_grid < 256) prep_grid = 256;   // hist blocks need 256 blocks

        prep_hist_kernel<<<prep_grid, 256, 0, stream>>>(
            x, W1, W2, W3, W4, xb, Wb, dst, bpart, M, nx4, NE);
        bucket_scan_kernel<<<1, 256, 0, stream>>>(bpart, boff, gcur, NB);
        bucketize_kernel<<<256, 512, 0, stream>>>(src, dst, gcur, bkt, NE, chunk);
        bucket_finalize_kernel<<<NB, 512, 0, stream>>>(bkt, boff, offs, deg, csr, M, NB);
        gather_kernel<true><<<(M + 3) / 4, 256, 0, stream>>>(xb, offs, csr, gb, M);
        gemm_kernel<true><<<(M + 31) / 32, 256, 0, stream>>>(
            xb, gb, deg, Wb, B1, B2, B3, B4, out, M);
    } else {
        // low-workspace fallback: fp32 gather + atomic hist + global scan + ranged fill
        unsigned short* gb = (unsigned short*)take(gb_bytes);
        unsigned short* Wb = (unsigned short*)take(wb_bytes);
        int* deg    = (int*)take((size_t)M * 4);
        int* offs   = (int*)take((size_t)(M + 1) * 4);
        int* cursor = (int*)take((size_t)M * 4);
        int* bsum   = (int*)take(256 * 4);
        int* csr    = (int*)take((size_t)NE * 4);

        const int prep_elems = (M > 16384 ? M : 16384);
        const int rangeSize = (M + 7) / 8;
        prep_kernel<<<(prep_elems + 255) / 256, 256, 0, stream>>>(
            x, W1, W2, W3, W4, nullptr, Wb, deg, M, 0);
        hist_kernel<<<(NE + 255) / 256, 256, 0, stream>>>(dst, deg, NE);
        scan_local_kernel<<<nbScan, 1024, 0, stream>>>(deg, offs, bsum, M);
        scan_totals_kernel<<<1, 128, 0, stream>>>(bsum, offs, nbScan, M);
        scan_finalize_kernel<<<nbScan, 1024, 0, stream>>>(offs, bsum, cursor, M);
        fill_csr_ranged_kernel<<<2048, 256, 0, stream>>>(src, dst, cursor, csr, NE, rangeSize);
        gather_kernel<false><<<(M + 3) / 4, 256, 0, stream>>>(x, offs, csr, gb, M);
        gemm_kernel<false><<<(M + 31) / 32, 256, 0, stream>>>(
            x, gb, deg, Wb, B1, B2, B3, B4, out, M);
    }
}

// Round 9
// 262.314 us; speedup vs baseline: 1.4093x; 1.0753x over previous
//
#include <hip/hip_runtime.h>

// ---------- fp32 <-> bf16 helpers ----------
__device__ __forceinline__ float bf2f(unsigned short u) {
    union { unsigned int i; float f; } v;
    v.i = ((unsigned int)u) << 16;
    return v.f;
}
__device__ __forceinline__ unsigned short f2bf(float f) {
    union { float f; unsigned int i; } v;
    v.f = f;
    unsigned int x = v.i;
    return (unsigned short)((x + 0x7fffu + ((x >> 16) & 1u)) >> 16);
}

typedef short bf16x8 __attribute__((ext_vector_type(8)));
typedef float f32x4 __attribute__((ext_vector_type(4)));

// bucket geometry: 512 nodes per bucket (shift 9); NB = ceil(M/512) <= 256
#define BSHIFT 9
#define BRANGE 512

// W panel permutation: panel-local offset so the gemm B-fragment load is one
// fully-coalesced 1KB wave read: off = ((cg*4+kk)*64 + quad*16 + ln)*8 + e
__device__ __forceinline__ int wperm(int i) {
    int col = i >> 7, k = i & 127;
    int cg = col >> 4, lnw = col & 15;
    int kkw = k >> 5, qw = (k >> 3) & 3, ew = k & 7;
    return (((cg * 4 + kkw) * 64) + qw * 16 + lnw) * 8 + ew;
}

// ---------- merged prep + bucket-histogram ----------
// All blocks: x fp32->bf16 and W panels -> bf16 (permuted layout). Blocks 0..255
// additionally build a per-block partial bucket histogram over a strided edge
// slice and write it to bpart[blk][0..255] with PLAIN stores.
__global__ __launch_bounds__(256) void prep_hist_kernel(
    const float* __restrict__ x,
    const float* __restrict__ W1, const float* __restrict__ W2,
    const float* __restrict__ W3, const float* __restrict__ W4,
    unsigned short* __restrict__ xb, unsigned short* __restrict__ Wb,
    const int* __restrict__ dst, int* __restrict__ bpart,
    int M, int nx4, int ne)
{
    __shared__ int h[256];
    const int t = threadIdx.x;
    const int blk = blockIdx.x;
    const bool histBlock = (blk < 256);
    if (histBlock) {               // block-uniform branch: barrier is safe
        h[t] = 0;
        __syncthreads();
    }

    int i = blk * 256 + t;
    if (i < nx4) {
        float4 v = ((const float4*)x)[i];
        unsigned lo = (unsigned)f2bf(v.x) | ((unsigned)f2bf(v.y) << 16);
        unsigned hi = (unsigned)f2bf(v.z) | ((unsigned)f2bf(v.w) << 16);
        uint2 p; p.x = lo; p.y = hi;
        *(uint2*)(xb + (size_t)i * 4) = p;
    }
    if (i < 16384) {
        int off = wperm(i);
        Wb[off]         = f2bf(W1[i]);
        Wb[16384 + off] = f2bf(W2[i]);
        Wb[32768 + off] = f2bf(W3[i] + W4[i]);
    }

    if (histBlock) {
        for (int e = blk * 256 + t; e < ne; e += 65536)
            atomicAdd(&h[dst[e] >> BSHIFT], 1);
        __syncthreads();
        bpart[blk * 256 + t] = h[t];   // plain store, fully overwritten
    }
}

// single block: reduce 256 partial histograms -> bucket counts -> scan ->
// boff[0..nb] (bucket offsets) and gcur (region cursors for bucketize)
__global__ __launch_bounds__(256) void bucket_scan_kernel(
    const int* __restrict__ bpart, int* __restrict__ boff, int* __restrict__ gcur, int nb)
{
    __shared__ int sh[256];
    int t = threadIdx.x;
    int v = 0;
    for (int k = 0; k < 256; ++k) v += bpart[k * 256 + t];   // coalesced per k
    if (t >= nb) v = 0;
    sh[t] = v;
    __syncthreads();
    int acc = v;
    for (int off = 1; off < 256; off <<= 1) {
        int y = (t >= off) ? sh[t - off] : 0;
        __syncthreads();
        acc += y;
        sh[t] = acc;
        __syncthreads();
    }
    if (t < nb) {
        boff[t + 1] = acc;        // inclusive
        gcur[t] = acc - v;        // exclusive: region cursor
    }
    if (t == 0) boff[0] = 0;
}

// Partition edges into dst-range buckets. Per block: LDS count pass, ONE global
// atomic per touched bucket to claim a contiguous run, then LDS-cursor scatter.
__global__ __launch_bounds__(512) void bucketize_kernel(
    const int* __restrict__ src, const int* __restrict__ dst,
    int* __restrict__ gcur, int2* __restrict__ bucketed, int ne, int chunk)
{
    __shared__ int cnt[256];
    __shared__ int sbase[256];
    const int t = threadIdx.x;
    const int e0 = blockIdx.x * chunk;
    const int e1 = (e0 + chunk < ne) ? e0 + chunk : ne;

    if (t < 256) cnt[t] = 0;
    __syncthreads();
    for (int e = e0 + t; e < e1; e += 512)
        atomicAdd(&cnt[dst[e] >> BSHIFT], 1);
    __syncthreads();
    if (t < 256) {
        int c = cnt[t];
        sbase[t] = c ? atomicAdd(&gcur[t], c) : 0;
        cnt[t] = 0;
    }
    __syncthreads();
    for (int e = e0 + t; e < e1; e += 512) {
        int d = dst[e];
        int b = d >> BSHIFT;
        int loc = atomicAdd(&cnt[b], 1);
        int2 v; v.x = src[e]; v.y = d;
        bucketed[sbase[b] + loc] = v;
    }
}

// ---------- merged finalize: per-bucket hist -> LDS scan -> offs/deg -> csr fill ----------
__global__ __launch_bounds__(512) void bucket_finalize_kernel(
    const int2* __restrict__ bucketed, const int* __restrict__ boff,
    int* __restrict__ offs, int* __restrict__ deg, int* __restrict__ csr,
    int M, int nb)
{
    __shared__ int cnt[BRANGE];
    __shared__ int sc[BRANGE];
    const int t = threadIdx.x;
    const int b = blockIdx.x;
    cnt[t] = 0;
    __syncthreads();
    const int lo = boff[b], hi = boff[b + 1];
    for (int i = lo + t; i < hi; i += 512)
        atomicAdd(&cnt[bucketed[i].y & (BRANGE - 1)], 1);
    __syncthreads();
    const int v = cnt[t];
    // Hillis-Steele inclusive scan over 512
    sc[t] = v;
    __syncthreads();
    int acc = v;
    for (int off = 1; off < 512; off <<= 1) {
        int y = (t >= off) ? sc[t - off] : 0;
        __syncthreads();
        acc += y;
        sc[t] = acc;
        __syncthreads();
    }
    const int excl = acc - v;
    const int node = (b << BSHIFT) + t;
    if (node < M) {
        offs[node] = lo + excl;
        deg[node] = v;
    }
    if (b == nb - 1 && t == 0) offs[M] = hi;   // grand total == NE
    // reuse cnt[] as cursors
    cnt[t] = lo + excl;
    __syncthreads();
    for (int i = lo + t; i < hi; i += 512) {
        int2 e = bucketed[i];
        int p = atomicAdd(&cnt[e.y & (BRANGE - 1)], 1);
        csr[p] = e.x;
    }
}

// ---------- fallback-path kernels (low workspace), proven ----------
__global__ void prep_kernel(const float* __restrict__ x,
                            const float* __restrict__ W1, const float* __restrict__ W2,
                            const float* __restrict__ W3, const float* __restrict__ W4,
                            unsigned short* __restrict__ xb, unsigned short* __restrict__ Wb,
                            int* __restrict__ deg, int M, int nx4)
{
    int i = blockIdx.x * 256 + threadIdx.x;
    if (i < nx4) {
        float4 v = ((const float4*)x)[i];
        unsigned lo = (unsigned)f2bf(v.x) | ((unsigned)f2bf(v.y) << 16);
        unsigned hi = (unsigned)f2bf(v.z) | ((unsigned)f2bf(v.w) << 16);
        uint2 p; p.x = lo; p.y = hi;
        *(uint2*)(xb + (size_t)i * 4) = p;
    }
    if (deg && i < M) deg[i] = 0;
    if (i < 16384) {
        int off = wperm(i);
        Wb[off]         = f2bf(W1[i]);
        Wb[16384 + off] = f2bf(W2[i]);
        Wb[32768 + off] = f2bf(W3[i] + W4[i]);
    }
}

__global__ void hist_kernel(const int* __restrict__ dst, int* __restrict__ deg, int ne) {
    int e = blockIdx.x * blockDim.x + threadIdx.x;
    if (e < ne) atomicAdd(&deg[dst[e]], 1);
}

__global__ __launch_bounds__(1024) void scan_local_kernel(
    const int* __restrict__ deg, int* __restrict__ offs, int* __restrict__ bsum, int n)
{
    __shared__ int sh[1024];
    int t = threadIdx.x;
    int i = blockIdx.x * 1024 + t;
    int v = (i < n) ? deg[i] : 0;
    sh[t] = v;
    __syncthreads();
    int acc = v;
    for (int off = 1; off < 1024; off <<= 1) {
        int y = (t >= off) ? sh[t - off] : 0;
        __syncthreads();
        acc += y;
        sh[t] = acc;
        __syncthreads();
    }
    if (i < n) offs[i] = acc - v;  // exclusive within block
    if (t == 1023) bsum[blockIdx.x] = acc;
}

__global__ __launch_bounds__(128) void scan_totals_kernel(
    int* __restrict__ bsum, int* __restrict__ offs, int nb, int n)
{
    __shared__ int sh[128];
    int t = threadIdx.x;
    int v = (t < nb) ? bsum[t] : 0;
    sh[t] = v;
    __syncthreads();
    int acc = v;
    for (int off = 1; off < 128; off <<= 1) {
        int y = (t >= off) ? sh[t - off] : 0;
        __syncthreads();
        acc += y;
        sh[t] = acc;
        __syncthreads();
    }
    if (t < nb) bsum[t] = acc - v;   // exclusive block offsets, in place
    if (t == 127) offs[n] = acc;     // grand total == NE
}

__global__ __launch_bounds__(1024) void scan_finalize_kernel(
    int* __restrict__ offs, const int* __restrict__ bsum, int* __restrict__ cursor, int n)
{
    int i = blockIdx.x * 1024 + threadIdx.x;
    if (i < n) {
        int o = offs[i] + bsum[i >> 10];
        offs[i] = o;
        if (cursor) cursor[i] = o;
    }
}

__global__ __launch_bounds__(256) void fill_csr_ranged_kernel(
    const int* __restrict__ src, const int* __restrict__ dst,
    int* __restrict__ cursor, int* __restrict__ csr, int ne, int rangeSize)
{
    const int r = blockIdx.x & 7;
    const int cb = blockIdx.x >> 3;
    const int nchunk = gridDim.x >> 3;
    const unsigned lo = (unsigned)(r * rangeSize);
    for (int e = cb * 256 + threadIdx.x; e < ne; e += nchunk * 256) {
        int d = dst[e];
        int s = src[e];
        if ((unsigned)(d - lo) < (unsigned)rangeSize) {
            int pos = atomicAdd(&cursor[d], 1);
            csr[pos] = s;
        }
    }
}

// ---------- gather: one wave per node, 8-deep masked unroll, bf16 out ----------
template<bool BF16SRC>
__global__ __launch_bounds__(256) void gather_kernel(
    const void* __restrict__ xsrc, const int* __restrict__ offs,
    const int* __restrict__ csr, unsigned short* __restrict__ gb, int M)
{
    const int wave = threadIdx.x >> 6;
    const int lane = threadIdx.x & 63;
    const int node = blockIdx.x * 4 + wave;
    if (node >= M) return;
    const int e0 = offs[node];
    const int e1 = offs[node + 1];

    float s0 = 0.f, s1 = 0.f, t0 = 0.f, t1 = 0.f;
    for (int e = e0; e < e1; e += 8) {
        int id[8];
        float m[8];
#pragma unroll
        for (int j = 0; j < 8; ++j) {
            int ee = e + j;
            bool ok = ee < e1;
            id[j] = csr[ok ? ee : e1 - 1];
            m[j] = ok ? 1.f : 0.f;
        }
#pragma unroll
        for (int j = 0; j < 8; ++j) {
            float lo, hi;
            if (BF16SRC) {
                unsigned v = *(const unsigned*)((const unsigned short*)xsrc +
                                                (size_t)id[j] * 128 + lane * 2);
                lo = bf2f((unsigned short)(v & 0xffffu));
                hi = bf2f((unsigned short)(v >> 16));
            } else {
                float2 v = *(const float2*)((const float*)xsrc +
                                            (size_t)id[j] * 128 + lane * 2);
                lo = v.x;
                hi = v.y;
            }
            if (j & 1) { t0 += m[j] * lo; t1 += m[j] * hi; }
            else       { s0 += m[j] * lo; s1 += m[j] * hi; }
        }
    }
    unsigned pk = (unsigned)f2bf(s0 + t0) | ((unsigned)f2bf(s1 + t1) << 16);
    *(unsigned*)(gb + (size_t)node * 128 + lane * 2) = pk;
}

// ---------- persistent, double-buffered 3-panel bf16 MFMA GEMM ----------
// Each block owns tiles {blockIdx.x, +stride, ...}. Pipeline: commit staged regs
// of tile t to LDS[cur], barrier, ISSUE global loads for tile t+stride, then
// compute tile t (MFMA + epilogue + nontemporal stores). HBM latency of the next
// tile hides under the current tile's compute; one barrier per tile; LDS buffers
// alternate so fast waves never clobber the buffer laggards still read.
// out = sigmoid(2*(P34 + d*(b3+b4))) * (2*(P2 + d*b2)) + P1 + b1
template<bool XBF16>
__global__ __launch_bounds__(256) void gemm_kernel(
    const void* __restrict__ xsrc, const unsigned short* __restrict__ gb,
    const int* __restrict__ deg, const unsigned short* __restrict__ Wb,
    const float* __restrict__ B1, const float* __restrict__ B2,
    const float* __restrict__ B3, const float* __restrict__ B4,
    float* __restrict__ out, int M, int nTiles)
{
    __shared__ unsigned short x_lds[2][32 * 136];
    __shared__ unsigned short g_lds[2][32 * 136];

    const int t = threadIdx.x;
    const int wave = t >> 6;
    const int lane = t & 63;
    const int ln = lane & 15;
    const int quad = lane >> 4;

    // bf16 staging geometry: 2 chunks of 16B per thread per array
    const int r0c = t >> 4,          k0c = (t & 15) * 8;
    const int r1c = (256 + t) >> 4,  k1c = ((256 + t) & 15) * 8;

    int tile = blockIdx.x;
    if (tile >= nTiles) return;
    const int stride = gridDim.x;

    uint4 rx0, rx1, rg0, rg1;
    float4 f0, f1, f2, f3;

    // ---- prologue: issue loads for first tile ----
    {
        const int row0 = tile * 32;
        if (XBF16) {
            const unsigned short* xb = (const unsigned short*)xsrc;
            int gr0 = row0 + r0c; if (gr0 > M - 1) gr0 = M - 1;
            int gr1 = row0 + r1c; if (gr1 > M - 1) gr1 = M - 1;
            rx0 = *(const uint4*)(xb + (size_t)gr0 * 128 + k0c);
            rx1 = *(const uint4*)(xb + (size_t)gr1 * 128 + k1c);
        } else {
            const float* xf = (const float*)xsrc;
            { int c = t;       int row = c >> 5, ko = (c & 31) * 4; int gr = row0 + row; if (gr > M - 1) gr = M - 1; f0 = *(const float4*)(xf + (size_t)gr * 128 + ko); }
            { int c = 256 + t; int row = c >> 5, ko = (c & 31) * 4; int gr = row0 + row; if (gr > M - 1) gr = M - 1; f1 = *(const float4*)(xf + (size_t)gr * 128 + ko); }
            { int c = 512 + t; int row = c >> 5, ko = (c & 31) * 4; int gr = row0 + row; if (gr > M - 1) gr = M - 1; f2 = *(const float4*)(xf + (size_t)gr * 128 + ko); }
            { int c = 768 + t; int row = c >> 5, ko = (c & 31) * 4; int gr = row0 + row; if (gr > M - 1) gr = M - 1; f3 = *(const float4*)(xf + (size_t)gr * 128 + ko); }
        }
        int gr0 = row0 + r0c; if (gr0 > M - 1) gr0 = M - 1;
        int gr1 = row0 + r1c; if (gr1 > M - 1) gr1 = M - 1;
        rg0 = *(const uint4*)(gb + (size_t)gr0 * 128 + k0c);
        rg1 = *(const uint4*)(gb + (size_t)gr1 * 128 + k1c);
    }

    int cur = 0;
    for (;;) {
        // ---- commit staged regs -> LDS[cur] ----
        if (XBF16) {
            *(uint4*)&x_lds[cur][r0c * 136 + k0c] = rx0;
            *(uint4*)&x_lds[cur][r1c * 136 + k1c] = rx1;
        } else {
            { int c = t;       int row = c >> 5, ko = (c & 31) * 4;
              unsigned p0 = (unsigned)f2bf(f0.x) | ((unsigned)f2bf(f0.y) << 16);
              unsigned p1 = (unsigned)f2bf(f0.z) | ((unsigned)f2bf(f0.w) << 16);
              *(unsigned*)&x_lds[cur][row * 136 + ko] = p0; *(unsigned*)&x_lds[cur][row * 136 + ko + 2] = p1; }
            { int c = 256 + t; int row = c >> 5, ko = (c & 31) * 4;
              unsigned p0 = (unsigned)f2bf(f1.x) | ((unsigned)f2bf(f1.y) << 16);
              unsigned p1 = (unsigned)f2bf(f1.z) | ((unsigned)f2bf(f1.w) << 16);
              *(unsigned*)&x_lds[cur][row * 136 + ko] = p0; *(unsigned*)&x_lds[cur][row * 136 + ko + 2] = p1; }
            { int c = 512 + t; int row = c >> 5, ko = (c & 31) * 4;
              unsigned p0 = (unsigned)f2bf(f2.x) | ((unsigned)f2bf(f2.y) << 16);
              unsigned p1 = (unsigned)f2bf(f2.z) | ((unsigned)f2bf(f2.w) << 16);
              *(unsigned*)&x_lds[cur][row * 136 + ko] = p0; *(unsigned*)&x_lds[cur][row * 136 + ko + 2] = p1; }
            { int c = 768 + t; int row = c >> 5, ko = (c & 31) * 4;
              unsigned p0 = (unsigned)f2bf(f3.x) | ((unsigned)f2bf(f3.y) << 16);
              unsigned p1 = (unsigned)f2bf(f3.z) | ((unsigned)f2bf(f3.w) << 16);
              *(unsigned*)&x_lds[cur][row * 136 + ko] = p0; *(unsigned*)&x_lds[cur][row * 136 + ko + 2] = p1; }
        }
        *(uint4*)&g_lds[cur][r0c * 136 + k0c] = rg0;
        *(uint4*)&g_lds[cur][r1c * 136 + k1c] = rg1;
        __syncthreads();

        const int row0 = tile * 32;
        const int nxt = tile + stride;
        if (nxt < nTiles) {
            // ---- issue next-tile loads; latency hides under compute below ----
            const int nrow0 = nxt * 32;
            if (XBF16) {
                const unsigned short* xb = (const unsigned short*)xsrc;
                int gr0 = nrow0 + r0c; if (gr0 > M - 1) gr0 = M - 1;
                int gr1 = nrow0 + r1c; if (gr1 > M - 1) gr1 = M - 1;
                rx0 = *(const uint4*)(xb + (size_t)gr0 * 128 + k0c);
                rx1 = *(const uint4*)(xb + (size_t)gr1 * 128 + k1c);
            } else {
                const float* xf = (const float*)xsrc;
                { int c = t;       int row = c >> 5, ko = (c & 31) * 4; int gr = nrow0 + row; if (gr > M - 1) gr = M - 1; f0 = *(const float4*)(xf + (size_t)gr * 128 + ko); }
                { int c = 256 + t; int row = c >> 5, ko = (c & 31) * 4; int gr = nrow0 + row; if (gr > M - 1) gr = M - 1; f1 = *(const float4*)(xf + (size_t)gr * 128 + ko); }
                { int c = 512 + t; int row = c >> 5, ko = (c & 31) * 4; int gr = nrow0 + row; if (gr > M - 1) gr = M - 1; f2 = *(const float4*)(xf + (size_t)gr * 128 + ko); }
                { int c = 768 + t; int row = c >> 5, ko = (c & 31) * 4; int gr = nrow0 + row; if (gr > M - 1) gr = M - 1; f3 = *(const float4*)(xf + (size_t)gr * 128 + ko); }
            }
            int gr0 = nrow0 + r0c; if (gr0 > M - 1) gr0 = M - 1;
            int gr1 = nrow0 + r1c; if (gr1 > M - 1) gr1 = M - 1;
            rg0 = *(const uint4*)(gb + (size_t)gr0 * 128 + k0c);
            rg1 = *(const uint4*)(gb + (size_t)gr1 * 128 + k1c);
        }

        // ---- 3-panel GEMM: wave owns cols [wave*32, wave*32+32), rows 0..31 ----
        f32x4 acc[3][2][2];
#pragma unroll
        for (int p = 0; p < 3; ++p)
#pragma unroll
            for (int rt = 0; rt < 2; ++rt)
#pragma unroll
                for (int c = 0; c < 2; ++c) {
                    acc[p][rt][c][0] = 0.f; acc[p][rt][c][1] = 0.f;
                    acc[p][rt][c][2] = 0.f; acc[p][rt][c][3] = 0.f;
                }

#pragma unroll
        for (int kk = 0; kk < 4; ++kk) {
            bf16x8 ax[2], ag[2];
#pragma unroll
            for (int rt = 0; rt < 2; ++rt) {
                ax[rt] = *(const bf16x8*)&x_lds[cur][(rt * 16 + ln) * 136 + kk * 32 + quad * 8];
                ag[rt] = *(const bf16x8*)&g_lds[cur][(rt * 16 + ln) * 136 + kk * 32 + quad * 8];
            }
#pragma unroll
            for (int p = 0; p < 3; ++p) {
#pragma unroll
                for (int c = 0; c < 2; ++c) {
                    // permuted W layout: one coalesced 1KB wave-load per fragment
                    bf16x8 bw = *(const bf16x8*)(Wb +
                        ((size_t)((p * 8 + wave * 2 + c) * 4 + kk) << 9) + lane * 8);
#pragma unroll
                    for (int rt = 0; rt < 2; ++rt) {
                        acc[p][rt][c] = __builtin_amdgcn_mfma_f32_16x16x32_bf16(
                            (p == 0) ? ax[rt] : ag[rt], bw, acc[p][rt][c], 0, 0, 0);
                    }
                }
            }
        }

        // ---- epilogue (fp32), nontemporal out stores ----
#pragma unroll
        for (int rt = 0; rt < 2; ++rt) {
#pragma unroll
            for (int i = 0; i < 4; ++i) {
                int row = row0 + rt * 16 + quad * 4 + i;
                if (row < M) {
                    float dg = (float)deg[row];
#pragma unroll
                    for (int c = 0; c < 2; ++c) {
                        int col = wave * 32 + c * 16 + ln;
                        float p1 = acc[0][rt][c][i] + B1[col];
                        float h2 = 2.f * (acc[1][rt][c][i] + dg * B2[col]);
                        float z  = 2.f * (acc[2][rt][c][i] + dg * (B3[col] + B4[col]));
                        float g = 1.f / (1.f + __expf(-z));
                        __builtin_nontemporal_store(g * h2 + p1,
                                                    &out[(size_t)row * 128 + col]);
                    }
                }
            }
        }

        if (nxt >= nTiles) break;
        tile = nxt;
        cur ^= 1;
    }
}

extern "C" void kernel_launch(void* const* d_in, const int* in_sizes, int n_in,
                              void* d_out, int out_size, void* d_ws, size_t ws_size,
                              hipStream_t stream) {
    const float* x  = (const float*)d_in[0];
    const int* eidx = (const int*)d_in[1];
    const float* W1 = (const float*)d_in[2];
    const float* B1 = (const float*)d_in[3];
    const float* W2 = (const float*)d_in[4];
    const float* B2 = (const float*)d_in[5];
    const float* W3 = (const float*)d_in[6];
    const float* B3 = (const float*)d_in[7];
    const float* W4 = (const float*)d_in[8];
    const float* B4 = (const float*)d_in[9];
    float* out      = (float*)d_out;

    const int M  = in_sizes[0] / 128;   // 100000 nodes
    const int NE = in_sizes[1] / 2;     // 1600000 edges
    const int* src = eidx;
    const int* dst = eidx + NE;

    const int NB = (M + BRANGE - 1) >> BSHIFT;   // buckets (196 for M=100000)

    auto pad = [](size_t b) { return (b + 127) & ~(size_t)127; };
    const size_t xb_bytes  = pad((size_t)M * 128 * 2);
    const size_t gb_bytes  = pad((size_t)M * 128 * 2);
    const size_t wb_bytes  = pad((size_t)3 * 16384 * 2);
    const size_t deg_bytes = pad((size_t)M * 4);
    const size_t off_bytes = pad((size_t)(M + 1) * 4);
    const size_t csr_bytes = pad((size_t)NE * 4);
    const size_t bkt_bytes = pad((size_t)NE * 8);
    const size_t bpart_bytes = pad((size_t)256 * 256 * 4);

    const size_t need_full = xb_bytes + gb_bytes + wb_bytes + deg_bytes + off_bytes +
                             csr_bytes + bkt_bytes + bpart_bytes + 4 * 1024;
    const bool full = (NB <= 256) && ws_size >= need_full + 1024;

    char* ws = (char*)d_ws;
    size_t off = 0;
    auto take = [&](size_t bytes) -> char* {
        char* p = ws + off;
        off = (off + bytes + 127) & ~(size_t)127;
        return p;
    };

    const int nbScan = (M + 1023) / 1024;
    const int nTiles = (M + 31) / 32;
    const int gemmGrid = nTiles < 1024 ? nTiles : 1024;

    if (full) {
        unsigned short* xb = (unsigned short*)take(xb_bytes);
        unsigned short* gb = (unsigned short*)take(gb_bytes);
        unsigned short* Wb = (unsigned short*)take(wb_bytes);
        int* deg    = (int*)take((size_t)M * 4);
        int* offs   = (int*)take((size_t)(M + 1) * 4);
        int* csr    = (int*)take((size_t)NE * 4);
        int2* bkt   = (int2*)take((size_t)NE * 8);
        int* bpart  = (int*)take((size_t)256 * 256 * 4);
        int* boff   = (int*)take(257 * 4);
        int* gcur   = (int*)take(256 * 4);

        const int nx4 = M * 128 / 4;
        const int chunk = (NE + 255) / 256;
        int prep_grid = (M * 32 + 255) / 256;
        if (prep_grid < 256) prep_grid = 256;   // hist blocks need 256 blocks

        prep_hist_kernel<<<prep_grid, 256, 0, stream>>>(
            x, W1, W2, W3, W4, xb, Wb, dst, bpart, M, nx4, NE);
        bucket_scan_kernel<<<1, 256, 0, stream>>>(bpart, boff, gcur, NB);
        bucketize_kernel<<<256, 512, 0, stream>>>(src, dst, gcur, bkt, NE, chunk);
        bucket_finalize_kernel<<<NB, 512, 0, stream>>>(bkt, boff, offs, deg, csr, M, NB);
        gather_kernel<true><<<(M + 3) / 4, 256, 0, stream>>>(xb, offs, csr, gb, M);
        gemm_kernel<true><<<gemmGrid, 256, 0, stream>>>(
            xb, gb, deg, Wb, B1, B2, B3, B4, out, M, nTiles);
    } else {
        // low-workspace fallback: fp32 gather + atomic hist + global scan + ranged fill
        unsigned short* gb = (unsigned short*)take(gb_bytes);
        unsigned short* Wb = (unsigned short*)take(wb_bytes);
        int* deg    = (int*)take((size_t)M * 4);
        int* offs   = (int*)take((size_t)(M + 1) * 4);
        int* cursor = (int*)take((size_t)M * 4);
        int* bsum   = (int*)take(256 * 4);
        int* csr    = (int*)take((size_t)NE * 4);

        const int prep_elems = (M > 16384 ? M : 16384);
        const int rangeSize = (M + 7) / 8;
        prep_kernel<<<(prep_elems + 255) / 256, 256, 0, stream>>>(
            x, W1, W2, W3, W4, nullptr, Wb, deg, M, 0);
        hist_kernel<<<(NE + 255) / 256, 256, 0, stream>>>(dst, deg, NE);
        scan_local_kernel<<<nbScan, 1024, 0, stream>>>(deg, offs, bsum, M);
        scan_totals_kernel<<<1, 128, 0, stream>>>(bsum, offs, nbScan, M);
        scan_finalize_kernel<<<nbScan, 1024, 0, stream>>>(offs, bsum, cursor, M);
        fill_csr_ranged_kernel<<<2048, 256, 0, stream>>>(src, dst, cursor, csr, NE, rangeSize);
        gather_kernel<false><<<(M + 3) / 4, 256, 0, stream>>>(x, offs, csr, gb, M);
        gemm_kernel<false><<<gemmGrid, 256, 0, stream>>>(
            x, gb, deg, Wb, B1, B2, B3, B4, out, M, nTiles);
    }
}

// Round 10
// 259.066 us; speedup vs baseline: 1.4270x; 1.0125x over previous
//
#include <hip/hip_runtime.h>

// ---------- fp32 <-> bf16 helpers ----------
__device__ __forceinline__ float bf2f(unsigned short u) {
    union { unsigned int i; float f; } v;
    v.i = ((unsigned int)u) << 16;
    return v.f;
}
__device__ __forceinline__ unsigned short f2bf(float f) {
    union { float f; unsigned int i; } v;
    v.f = f;
    unsigned int x = v.i;
    return (unsigned short)((x + 0x7fffu + ((x >> 16) & 1u)) >> 16);
}
__device__ __forceinline__ float bfbits(unsigned int bits) {
    union { unsigned int i; float f; } v;
    v.i = bits;
    return v.f;
}

typedef short bf16x8 __attribute__((ext_vector_type(8)));
typedef float f32x4 __attribute__((ext_vector_type(4)));

// bucket geometry: 512 nodes per bucket (shift 9); NB = ceil(M/512) <= 256
#define BSHIFT 9
#define BRANGE 512

// W panel permutation: panel-local offset so the gemm B-fragment load is one
// fully-coalesced 1KB wave read: off = ((cg*4+kk)*64 + quad*16 + ln)*8 + e
__device__ __forceinline__ int wperm(int i) {
    int col = i >> 7, k = i & 127;
    int cg = col >> 4, lnw = col & 15;
    int kkw = k >> 5, qw = (k >> 3) & 3, ew = k & 7;
    return (((cg * 4 + kkw) * 64) + qw * 16 + lnw) * 8 + ew;
}

// ---------- merged prep + bucket-histogram ----------
// All blocks: x fp32->bf16 and W panels -> bf16 (permuted layout). Blocks 0..255
// additionally build a per-block partial bucket histogram over a strided edge
// slice and write it to bpart[blk][0..255] with PLAIN stores.
__global__ __launch_bounds__(256) void prep_hist_kernel(
    const float* __restrict__ x,
    const float* __restrict__ W1, const float* __restrict__ W2,
    const float* __restrict__ W3, const float* __restrict__ W4,
    unsigned short* __restrict__ xb, unsigned short* __restrict__ Wb,
    const int* __restrict__ dst, int* __restrict__ bpart,
    int M, int nx4, int ne)
{
    __shared__ int h[256];
    const int t = threadIdx.x;
    const int blk = blockIdx.x;
    const bool histBlock = (blk < 256);
    if (histBlock) {               // block-uniform branch: barrier is safe
        h[t] = 0;
        __syncthreads();
    }

    int i = blk * 256 + t;
    if (i < nx4) {
        float4 v = ((const float4*)x)[i];
        unsigned lo = (unsigned)f2bf(v.x) | ((unsigned)f2bf(v.y) << 16);
        unsigned hi = (unsigned)f2bf(v.z) | ((unsigned)f2bf(v.w) << 16);
        uint2 p; p.x = lo; p.y = hi;
        *(uint2*)(xb + (size_t)i * 4) = p;
    }
    if (i < 16384) {
        int off = wperm(i);
        Wb[off]         = f2bf(W1[i]);
        Wb[16384 + off] = f2bf(W2[i]);
        Wb[32768 + off] = f2bf(W3[i] + W4[i]);
    }

    if (histBlock) {
        for (int e = blk * 256 + t; e < ne; e += 65536)
            atomicAdd(&h[dst[e] >> BSHIFT], 1);
        __syncthreads();
        bpart[blk * 256 + t] = h[t];   // plain store, fully overwritten
    }
}

// single block: reduce 256 partial histograms -> bucket counts -> scan ->
// boff[0..nb] (bucket offsets) and gcur (region cursors for bucketize)
__global__ __launch_bounds__(256) void bucket_scan_kernel(
    const int* __restrict__ bpart, int* __restrict__ boff, int* __restrict__ gcur, int nb)
{
    __shared__ int sh[256];
    int t = threadIdx.x;
    int v = 0;
    for (int k = 0; k < 256; ++k) v += bpart[k * 256 + t];   // coalesced per k
    if (t >= nb) v = 0;
    sh[t] = v;
    __syncthreads();
    int acc = v;
    for (int off = 1; off < 256; off <<= 1) {
        int y = (t >= off) ? sh[t - off] : 0;
        __syncthreads();
        acc += y;
        sh[t] = acc;
        __syncthreads();
    }
    if (t < nb) {
        boff[t + 1] = acc;        // inclusive
        gcur[t] = acc - v;        // exclusive: region cursor
    }
    if (t == 0) boff[0] = 0;
}

// Partition edges into dst-range buckets. Per block: LDS count pass, ONE global
// atomic per touched bucket to claim a contiguous run, then LDS-cursor scatter.
__global__ __launch_bounds__(512) void bucketize_kernel(
    const int* __restrict__ src, const int* __restrict__ dst,
    int* __restrict__ gcur, int2* __restrict__ bucketed, int ne, int chunk)
{
    __shared__ int cnt[256];
    __shared__ int sbase[256];
    const int t = threadIdx.x;
    const int e0 = blockIdx.x * chunk;
    const int e1 = (e0 + chunk < ne) ? e0 + chunk : ne;

    if (t < 256) cnt[t] = 0;
    __syncthreads();
    for (int e = e0 + t; e < e1; e += 512)
        atomicAdd(&cnt[dst[e] >> BSHIFT], 1);
    __syncthreads();
    if (t < 256) {
        int c = cnt[t];
        sbase[t] = c ? atomicAdd(&gcur[t], c) : 0;
        cnt[t] = 0;
    }
    __syncthreads();
    for (int e = e0 + t; e < e1; e += 512) {
        int d = dst[e];
        int b = d >> BSHIFT;
        int loc = atomicAdd(&cnt[b], 1);
        int2 v; v.x = src[e]; v.y = d;
        bucketed[sbase[b] + loc] = v;
    }
}

// ---------- merged finalize: per-bucket hist -> LDS scan -> offs/deg -> csr fill ----------
__global__ __launch_bounds__(512) void bucket_finalize_kernel(
    const int2* __restrict__ bucketed, const int* __restrict__ boff,
    int* __restrict__ offs, int* __restrict__ deg, int* __restrict__ csr,
    int M, int nb)
{
    __shared__ int cnt[BRANGE];
    __shared__ int sc[BRANGE];
    const int t = threadIdx.x;
    const int b = blockIdx.x;
    cnt[t] = 0;
    __syncthreads();
    const int lo = boff[b], hi = boff[b + 1];
    for (int i = lo + t; i < hi; i += 512)
        atomicAdd(&cnt[bucketed[i].y & (BRANGE - 1)], 1);
    __syncthreads();
    const int v = cnt[t];
    // Hillis-Steele inclusive scan over 512
    sc[t] = v;
    __syncthreads();
    int acc = v;
    for (int off = 1; off < 512; off <<= 1) {
        int y = (t >= off) ? sc[t - off] : 0;
        __syncthreads();
        acc += y;
        sc[t] = acc;
        __syncthreads();
    }
    const int excl = acc - v;
    const int node = (b << BSHIFT) + t;
    if (node < M) {
        offs[node] = lo + excl;
        deg[node] = v;
    }
    if (b == nb - 1 && t == 0) offs[M] = hi;   // grand total == NE
    // reuse cnt[] as cursors
    cnt[t] = lo + excl;
    __syncthreads();
    for (int i = lo + t; i < hi; i += 512) {
        int2 e = bucketed[i];
        int p = atomicAdd(&cnt[e.y & (BRANGE - 1)], 1);
        csr[p] = e.x;
    }
}

// ---------- fallback-path kernels (low workspace), proven ----------
__global__ void prep_kernel(const float* __restrict__ x,
                            const float* __restrict__ W1, const float* __restrict__ W2,
                            const float* __restrict__ W3, const float* __restrict__ W4,
                            unsigned short* __restrict__ xb, unsigned short* __restrict__ Wb,
                            int* __restrict__ deg, int M, int nx4)
{
    int i = blockIdx.x * 256 + threadIdx.x;
    if (i < nx4) {
        float4 v = ((const float4*)x)[i];
        unsigned lo = (unsigned)f2bf(v.x) | ((unsigned)f2bf(v.y) << 16);
        unsigned hi = (unsigned)f2bf(v.z) | ((unsigned)f2bf(v.w) << 16);
        uint2 p; p.x = lo; p.y = hi;
        *(uint2*)(xb + (size_t)i * 4) = p;
    }
    if (deg && i < M) deg[i] = 0;
    if (i < 16384) {
        int off = wperm(i);
        Wb[off]         = f2bf(W1[i]);
        Wb[16384 + off] = f2bf(W2[i]);
        Wb[32768 + off] = f2bf(W3[i] + W4[i]);
    }
}

__global__ void hist_kernel(const int* __restrict__ dst, int* __restrict__ deg, int ne) {
    int e = blockIdx.x * blockDim.x + threadIdx.x;
    if (e < ne) atomicAdd(&deg[dst[e]], 1);
}

__global__ __launch_bounds__(1024) void scan_local_kernel(
    const int* __restrict__ deg, int* __restrict__ offs, int* __restrict__ bsum, int n)
{
    __shared__ int sh[1024];
    int t = threadIdx.x;
    int i = blockIdx.x * 1024 + t;
    int v = (i < n) ? deg[i] : 0;
    sh[t] = v;
    __syncthreads();
    int acc = v;
    for (int off = 1; off < 1024; off <<= 1) {
        int y = (t >= off) ? sh[t - off] : 0;
        __syncthreads();
        acc += y;
        sh[t] = acc;
        __syncthreads();
    }
    if (i < n) offs[i] = acc - v;  // exclusive within block
    if (t == 1023) bsum[blockIdx.x] = acc;
}

__global__ __launch_bounds__(128) void scan_totals_kernel(
    int* __restrict__ bsum, int* __restrict__ offs, int nb, int n)
{
    __shared__ int sh[128];
    int t = threadIdx.x;
    int v = (t < nb) ? bsum[t] : 0;
    sh[t] = v;
    __syncthreads();
    int acc = v;
    for (int off = 1; off < 128; off <<= 1) {
        int y = (t >= off) ? sh[t - off] : 0;
        __syncthreads();
        acc += y;
        sh[t] = acc;
        __syncthreads();
    }
    if (t < nb) bsum[t] = acc - v;   // exclusive block offsets, in place
    if (t == 127) offs[n] = acc;     // grand total == NE
}

__global__ __launch_bounds__(1024) void scan_finalize_kernel(
    int* __restrict__ offs, const int* __restrict__ bsum, int* __restrict__ cursor, int n)
{
    int i = blockIdx.x * 1024 + threadIdx.x;
    if (i < n) {
        int o = offs[i] + bsum[i >> 10];
        offs[i] = o;
        if (cursor) cursor[i] = o;
    }
}

__global__ __launch_bounds__(256) void fill_csr_ranged_kernel(
    const int* __restrict__ src, const int* __restrict__ dst,
    int* __restrict__ cursor, int* __restrict__ csr, int ne, int rangeSize)
{
    const int r = blockIdx.x & 7;
    const int cb = blockIdx.x >> 3;
    const int nchunk = gridDim.x >> 3;
    const unsigned lo = (unsigned)(r * rangeSize);
    for (int e = cb * 256 + threadIdx.x; e < ne; e += nchunk * 256) {
        int d = dst[e];
        int s = src[e];
        if ((unsigned)(d - lo) < (unsigned)rangeSize) {
            int pos = atomicAdd(&cursor[d], 1);
            csr[pos] = s;
        }
    }
}

// ---------- pair-gather: half-wave per edge, uint2 loads ----------
// Lanes 0-31 process even edges, lanes 32-63 odd edges; each lane loads 8B
// (4 bf16 features at (lane&31)*4). One VMEM instruction covers 2 edges
// (vs 1 before): halves VMEM instruction count (2x bytes in flight per
// outstanding-request slot) and cuts per-edge VALU (~25-40%). Halves are
// merged with one shfl_xor(32) per accumulator; lanes 0-31 write uint2.
template<bool BF16SRC>
__global__ __launch_bounds__(256) void gather_kernel(
    const void* __restrict__ xsrc, const int* __restrict__ offs,
    const int* __restrict__ csr, unsigned short* __restrict__ gb, int M)
{
    const int wave = threadIdx.x >> 6;
    const int lane = threadIdx.x & 63;
    const int half = lane >> 5;        // 0: even edges, 1: odd edges
    const int fl   = lane & 31;        // features [4*fl, 4*fl+4)
    const int node = blockIdx.x * 4 + wave;
    if (node >= M) return;
    const int e0 = offs[node];
    const int e1 = offs[node + 1];

    float a0 = 0.f, a1 = 0.f, a2 = 0.f, a3 = 0.f;
    // 4 pairs per iteration = 8 edges (same masked-tail waste as proven 8-deep)
    for (int e = e0; e < e1; e += 8) {
        int id[4];
        float m[4];
#pragma unroll
        for (int j = 0; j < 4; ++j) {
            int ee = e + 2 * j + half;
            bool ok = ee < e1;
            id[j] = csr[ok ? ee : e1 - 1];
            m[j] = ok ? 1.f : 0.f;
        }
#pragma unroll
        for (int j = 0; j < 4; ++j) {
            if (BF16SRC) {
                uint2 v = *(const uint2*)((const unsigned short*)xsrc +
                                          (size_t)id[j] * 128 + fl * 4);
                // 4 bf16: [f0|f1<<16][f2|f3<<16]; bf->f32 is 1 shl / 1 and each
                a0 += m[j] * bfbits(v.x << 16);
                a1 += m[j] * bfbits(v.x & 0xffff0000u);
                a2 += m[j] * bfbits(v.y << 16);
                a3 += m[j] * bfbits(v.y & 0xffff0000u);
            } else {
                float4 v = *(const float4*)((const float*)xsrc +
                                            (size_t)id[j] * 128 + fl * 4);
                a0 += m[j] * v.x;
                a1 += m[j] * v.y;
                a2 += m[j] * v.z;
                a3 += m[j] * v.w;
            }
        }
    }
    // merge even/odd halves (features depend only on lane&31)
    a0 += __shfl_xor(a0, 32);
    a1 += __shfl_xor(a1, 32);
    a2 += __shfl_xor(a2, 32);
    a3 += __shfl_xor(a3, 32);
    if (half == 0) {
        uint2 pk;
        pk.x = (unsigned)f2bf(a0) | ((unsigned)f2bf(a1) << 16);
        pk.y = (unsigned)f2bf(a2) | ((unsigned)f2bf(a3) << 16);
        *(uint2*)(gb + (size_t)node * 128 + fl * 4) = pk;
    }
}

// ---------- persistent, double-buffered 3-panel bf16 MFMA GEMM (proven r9) ----------
// out = sigmoid(2*(P34 + d*(b3+b4))) * (2*(P2 + d*b2)) + P1 + b1
template<bool XBF16>
__global__ __launch_bounds__(256) void gemm_kernel(
    const void* __restrict__ xsrc, const unsigned short* __restrict__ gb,
    const int* __restrict__ deg, const unsigned short* __restrict__ Wb,
    const float* __restrict__ B1, const float* __restrict__ B2,
    const float* __restrict__ B3, const float* __restrict__ B4,
    float* __restrict__ out, int M, int nTiles)
{
    __shared__ unsigned short x_lds[2][32 * 136];
    __shared__ unsigned short g_lds[2][32 * 136];

    const int t = threadIdx.x;
    const int wave = t >> 6;
    const int lane = t & 63;
    const int ln = lane & 15;
    const int quad = lane >> 4;

    // bf16 staging geometry: 2 chunks of 16B per thread per array
    const int r0c = t >> 4,          k0c = (t & 15) * 8;
    const int r1c = (256 + t) >> 4,  k1c = ((256 + t) & 15) * 8;

    int tile = blockIdx.x;
    if (tile >= nTiles) return;
    const int stride = gridDim.x;

    uint4 rx0, rx1, rg0, rg1;
    float4 f0, f1, f2, f3;

    // ---- prologue: issue loads for first tile ----
    {
        const int row0 = tile * 32;
        if (XBF16) {
            const unsigned short* xb = (const unsigned short*)xsrc;
            int gr0 = row0 + r0c; if (gr0 > M - 1) gr0 = M - 1;
            int gr1 = row0 + r1c; if (gr1 > M - 1) gr1 = M - 1;
            rx0 = *(const uint4*)(xb + (size_t)gr0 * 128 + k0c);
            rx1 = *(const uint4*)(xb + (size_t)gr1 * 128 + k1c);
        } else {
            const float* xf = (const float*)xsrc;
            { int c = t;       int row = c >> 5, ko = (c & 31) * 4; int gr = row0 + row; if (gr > M - 1) gr = M - 1; f0 = *(const float4*)(xf + (size_t)gr * 128 + ko); }
            { int c = 256 + t; int row = c >> 5, ko = (c & 31) * 4; int gr = row0 + row; if (gr > M - 1) gr = M - 1; f1 = *(const float4*)(xf + (size_t)gr * 128 + ko); }
            { int c = 512 + t; int row = c >> 5, ko = (c & 31) * 4; int gr = row0 + row; if (gr > M - 1) gr = M - 1; f2 = *(const float4*)(xf + (size_t)gr * 128 + ko); }
            { int c = 768 + t; int row = c >> 5, ko = (c & 31) * 4; int gr = row0 + row; if (gr > M - 1) gr = M - 1; f3 = *(const float4*)(xf + (size_t)gr * 128 + ko); }
        }
        int gr0 = row0 + r0c; if (gr0 > M - 1) gr0 = M - 1;
        int gr1 = row0 + r1c; if (gr1 > M - 1) gr1 = M - 1;
        rg0 = *(const uint4*)(gb + (size_t)gr0 * 128 + k0c);
        rg1 = *(const uint4*)(gb + (size_t)gr1 * 128 + k1c);
    }

    int cur = 0;
    for (;;) {
        // ---- commit staged regs -> LDS[cur] ----
        if (XBF16) {
            *(uint4*)&x_lds[cur][r0c * 136 + k0c] = rx0;
            *(uint4*)&x_lds[cur][r1c * 136 + k1c] = rx1;
        } else {
            { int c = t;       int row = c >> 5, ko = (c & 31) * 4;
              unsigned p0 = (unsigned)f2bf(f0.x) | ((unsigned)f2bf(f0.y) << 16);
              unsigned p1 = (unsigned)f2bf(f0.z) | ((unsigned)f2bf(f0.w) << 16);
              *(unsigned*)&x_lds[cur][row * 136 + ko] = p0; *(unsigned*)&x_lds[cur][row * 136 + ko + 2] = p1; }
            { int c = 256 + t; int row = c >> 5, ko = (c & 31) * 4;
              unsigned p0 = (unsigned)f2bf(f1.x) | ((unsigned)f2bf(f1.y) << 16);
              unsigned p1 = (unsigned)f2bf(f1.z) | ((unsigned)f2bf(f1.w) << 16);
              *(unsigned*)&x_lds[cur][row * 136 + ko] = p0; *(unsigned*)&x_lds[cur][row * 136 + ko + 2] = p1; }
            { int c = 512 + t; int row = c >> 5, ko = (c & 31) * 4;
              unsigned p0 = (unsigned)f2bf(f2.x) | ((unsigned)f2bf(f2.y) << 16);
              unsigned p1 = (unsigned)f2bf(f2.z) | ((unsigned)f2bf(f2.w) << 16);
              *(unsigned*)&x_lds[cur][row * 136 + ko] = p0; *(unsigned*)&x_lds[cur][row * 136 + ko + 2] = p1; }
            { int c = 768 + t; int row = c >> 5, ko = (c & 31) * 4;
              unsigned p0 = (unsigned)f2bf(f3.x) | ((unsigned)f2bf(f3.y) << 16);
              unsigned p1 = (unsigned)f2bf(f3.z) | ((unsigned)f2bf(f3.w) << 16);
              *(unsigned*)&x_lds[cur][row * 136 + ko] = p0; *(unsigned*)&x_lds[cur][row * 136 + ko + 2] = p1; }
        }
        *(uint4*)&g_lds[cur][r0c * 136 + k0c] = rg0;
        *(uint4*)&g_lds[cur][r1c * 136 + k1c] = rg1;
        __syncthreads();

        const int row0 = tile * 32;
        const int nxt = tile + stride;
        if (nxt < nTiles) {
            // ---- issue next-tile loads; latency hides under compute below ----
            const int nrow0 = nxt * 32;
            if (XBF16) {
                const unsigned short* xb = (const unsigned short*)xsrc;
                int gr0 = nrow0 + r0c; if (gr0 > M - 1) gr0 = M - 1;
                int gr1 = nrow0 + r1c; if (gr1 > M - 1) gr1 = M - 1;
                rx0 = *(const uint4*)(xb + (size_t)gr0 * 128 + k0c);
                rx1 = *(const uint4*)(xb + (size_t)gr1 * 128 + k1c);
            } else {
                const float* xf = (const float*)xsrc;
                { int c = t;       int row = c >> 5, ko = (c & 31) * 4; int gr = nrow0 + row; if (gr > M - 1) gr = M - 1; f0 = *(const float4*)(xf + (size_t)gr * 128 + ko); }
                { int c = 256 + t; int row = c >> 5, ko = (c & 31) * 4; int gr = nrow0 + row; if (gr > M - 1) gr = M - 1; f1 = *(const float4*)(xf + (size_t)gr * 128 + ko); }
                { int c = 512 + t; int row = c >> 5, ko = (c & 31) * 4; int gr = nrow0 + row; if (gr > M - 1) gr = M - 1; f2 = *(const float4*)(xf + (size_t)gr * 128 + ko); }
                { int c = 768 + t; int row = c >> 5, ko = (c & 31) * 4; int gr = nrow0 + row; if (gr > M - 1) gr = M - 1; f3 = *(const float4*)(xf + (size_t)gr * 128 + ko); }
            }
            int gr0 = nrow0 + r0c; if (gr0 > M - 1) gr0 = M - 1;
            int gr1 = nrow0 + r1c; if (gr1 > M - 1) gr1 = M - 1;
            rg0 = *(const uint4*)(gb + (size_t)gr0 * 128 + k0c);
            rg1 = *(const uint4*)(gb + (size_t)gr1 * 128 + k1c);
        }

        // ---- 3-panel GEMM: wave owns cols [wave*32, wave*32+32), rows 0..31 ----
        f32x4 acc[3][2][2];
#pragma unroll
        for (int p = 0; p < 3; ++p)
#pragma unroll
            for (int rt = 0; rt < 2; ++rt)
#pragma unroll
                for (int c = 0; c < 2; ++c) {
                    acc[p][rt][c][0] = 0.f; acc[p][rt][c][1] = 0.f;
                    acc[p][rt][c][2] = 0.f; acc[p][rt][c][3] = 0.f;
                }

#pragma unroll
        for (int kk = 0; kk < 4; ++kk) {
            bf16x8 ax[2], ag[2];
#pragma unroll
            for (int rt = 0; rt < 2; ++rt) {
                ax[rt] = *(const bf16x8*)&x_lds[cur][(rt * 16 + ln) * 136 + kk * 32 + quad * 8];
                ag[rt] = *(const bf16x8*)&g_lds[cur][(rt * 16 + ln) * 136 + kk * 32 + quad * 8];
            }
#pragma unroll
            for (int p = 0; p < 3; ++p) {
#pragma unroll
                for (int c = 0; c < 2; ++c) {
                    // permuted W layout: one coalesced 1KB wave-load per fragment
                    bf16x8 bw = *(const bf16x8*)(Wb +
                        ((size_t)((p * 8 + wave * 2 + c) * 4 + kk) << 9) + lane * 8);
#pragma unroll
                    for (int rt = 0; rt < 2; ++rt) {
                        acc[p][rt][c] = __builtin_amdgcn_mfma_f32_16x16x32_bf16(
                            (p == 0) ? ax[rt] : ag[rt], bw, acc[p][rt][c], 0, 0, 0);
                    }
                }
            }
        }

        // ---- epilogue (fp32), nontemporal out stores ----
#pragma unroll
        for (int rt = 0; rt < 2; ++rt) {
#pragma unroll
            for (int i = 0; i < 4; ++i) {
                int row = row0 + rt * 16 + quad * 4 + i;
                if (row < M) {
                    float dg = (float)deg[row];
#pragma unroll
                    for (int c = 0; c < 2; ++c) {
                        int col = wave * 32 + c * 16 + ln;
                        float p1 = acc[0][rt][c][i] + B1[col];
                        float h2 = 2.f * (acc[1][rt][c][i] + dg * B2[col]);
                        float z  = 2.f * (acc[2][rt][c][i] + dg * (B3[col] + B4[col]));
                        float g = 1.f / (1.f + __expf(-z));
                        __builtin_nontemporal_store(g * h2 + p1,
                                                    &out[(size_t)row * 128 + col]);
                    }
                }
            }
        }

        if (nxt >= nTiles) break;
        tile = nxt;
        cur ^= 1;
    }
}

extern "C" void kernel_launch(void* const* d_in, const int* in_sizes, int n_in,
                              void* d_out, int out_size, void* d_ws, size_t ws_size,
                              hipStream_t stream) {
    const float* x  = (const float*)d_in[0];
    const int* eidx = (const int*)d_in[1];
    const float* W1 = (const float*)d_in[2];
    const float* B1 = (const float*)d_in[3];
    const float* W2 = (const float*)d_in[4];
    const float* B2 = (const float*)d_in[5];
    const float* W3 = (const float*)d_in[6];
    const float* B3 = (const float*)d_in[7];
    const float* W4 = (const float*)d_in[8];
    const float* B4 = (const float*)d_in[9];
    float* out      = (float*)d_out;

    const int M  = in_sizes[0] / 128;   // 100000 nodes
    const int NE = in_sizes[1] / 2;     // 1600000 edges
    const int* src = eidx;
    const int* dst = eidx + NE;

    const int NB = (M + BRANGE - 1) >> BSHIFT;   // buckets (196 for M=100000)

    auto pad = [](size_t b) { return (b + 127) & ~(size_t)127; };
    const size_t xb_bytes  = pad((size_t)M * 128 * 2);
    const size_t gb_bytes  = pad((size_t)M * 128 * 2);
    const size_t wb_bytes  = pad((size_t)3 * 16384 * 2);
    const size_t deg_bytes = pad((size_t)M * 4);
    const size_t off_bytes = pad((size_t)(M + 1) * 4);
    const size_t csr_bytes = pad((size_t)NE * 4);
    const size_t bkt_bytes = pad((size_t)NE * 8);
    const size_t bpart_bytes = pad((size_t)256 * 256 * 4);

    const size_t need_full = xb_bytes + gb_bytes + wb_bytes + deg_bytes + off_bytes +
                             csr_bytes + bkt_bytes + bpart_bytes + 4 * 1024;
    const bool full = (NB <= 256) && ws_size >= need_full + 1024;

    char* ws = (char*)d_ws;
    size_t off = 0;
    auto take = [&](size_t bytes) -> char* {
        char* p = ws + off;
        off = (off + bytes + 127) & ~(size_t)127;
        return p;
    };

    const int nbScan = (M + 1023) / 1024;
    const int nTiles = (M + 31) / 32;
    const int gemmGrid = nTiles < 1024 ? nTiles : 1024;

    if (full) {
        unsigned short* xb = (unsigned short*)take(xb_bytes);
        unsigned short* gb = (unsigned short*)take(gb_bytes);
        unsigned short* Wb = (unsigned short*)take(wb_bytes);
        int* deg    = (int*)take((size_t)M * 4);
        int* offs   = (int*)take((size_t)(M + 1) * 4);
        int* csr    = (int*)take((size_t)NE * 4);
        int2* bkt   = (int2*)take((size_t)NE * 8);
        int* bpart  = (int*)take((size_t)256 * 256 * 4);
        int* boff   = (int*)take(257 * 4);
        int* gcur   = (int*)take(256 * 4);

        const int nx4 = M * 128 / 4;
        const int chunk = (NE + 255) / 256;
        int prep_grid = (M * 32 + 255) / 256;
        if (prep_grid < 256) prep_grid = 256;   // hist blocks need 256 blocks

        prep_hist_kernel<<<prep_grid, 256, 0, stream>>>(
            x, W1, W2, W3, W4, xb, Wb, dst, bpart, M, nx4, NE);
        bucket_scan_kernel<<<1, 256, 0, stream>>>(bpart, boff, gcur, NB);
        bucketize_kernel<<<256, 512, 0, stream>>>(src, dst, gcur, bkt, NE, chunk);
        bucket_finalize_kernel<<<NB, 512, 0, stream>>>(bkt, boff, offs, deg, csr, M, NB);
        gather_kernel<true><<<(M + 3) / 4, 256, 0, stream>>>(xb, offs, csr, gb, M);
        gemm_kernel<true><<<gemmGrid, 256, 0, stream>>>(
            xb, gb, deg, Wb, B1, B2, B3, B4, out, M, nTiles);
    } else {
        // low-workspace fallback: fp32 gather + atomic hist + global scan + ranged fill
        unsigned short* gb = (unsigned short*)take(gb_bytes);
        unsigned short* Wb = (unsigned short*)take(wb_bytes);
        int* deg    = (int*)take((size_t)M * 4);
        int* offs   = (int*)take((size_t)(M + 1) * 4);
        int* cursor = (int*)take((size_t)M * 4);
        int* bsum   = (int*)take(256 * 4);
        int* csr    = (int*)take((size_t)NE * 4);

        const int prep_elems = (M > 16384 ? M : 16384);
        const int rangeSize = (M + 7) / 8;
        prep_kernel<<<(prep_elems + 255) / 256, 256, 0, stream>>>(
            x, W1, W2, W3, W4, nullptr, Wb, deg, M, 0);
        hist_kernel<<<(NE + 255) / 256, 256, 0, stream>>>(dst, deg, NE);
        scan_local_kernel<<<nbScan, 1024, 0, stream>>>(deg, offs, bsum, M);
        scan_totals_kernel<<<1, 128, 0, stream>>>(bsum, offs, nbScan, M);
        scan_finalize_kernel<<<nbScan, 1024, 0, stream>>>(offs, bsum, cursor, M);
        fill_csr_ranged_kernel<<<2048, 256, 0, stream>>>(src, dst, cursor, csr, NE, rangeSize);
        gather_kernel<false><<<(M + 3) / 4, 256, 0, stream>>>(x, offs, csr, gb, M);
        gemm_kernel<false><<<gemmGrid, 256, 0, stream>>>(
            x, gb, deg, Wb, B1, B2, B3, B4, out, M, nTiles);
    }
}